// Round 8
// baseline (1838.748 us; speedup 1.0000x reference)
//
#include <hip/hip_runtime.h>
#include <hip/hip_bf16.h>
#include <stdint.h>

// MaskedDeepDAN on MI355X (gfx950). B=8192, D_IN=2048, H=1024, C=1000.
// R14: R12/R13 had IDENTICAL absmax (0.2676 = max|ref| vs the memset-zero
// output) -> the cooperative kernel NEVER RAN: hipLaunchCooperativeKernel is
// not graph-capturable (harness times via hip graph). Same fused structure,
// but launched as a PLAIN kernel with a hand-rolled device-scope grid
// barrier (persistent-kernel pattern):
//   gbar(p): threadfence(release/wb) -> syncthreads -> t0: agent-scope
//   atomic add + spin (s_sleep) until bar[p]==gridDim.x -> syncthreads ->
//   threadfence(acquire/inv). 7 one-shot counters, zeroed by
//   hipMemsetAsync(d_ws,0,128,stream) preceding the launch (capturable).
// Deadlock safety: barrier needs all 512 blocks resident; launch_bounds
// (256,2) + 64KB LDS => exactly 2 blocks/CU x 256 CU = 512 slots.
// Phases: 0 detect (block 0) | 1 prep (all blocks) | 2..: six GEMM layers
// with gbar between. GEMM = R10 verbatim (best verified: 515us), runtime-
// parameterized: 128x128 tile BK=64, 4 waves, half-tile-pipelined frags,
// 2 barriers/tile, counted vmcnt(8) never 0 in main loop, XOR-swizzled
// staging/reads (bank-conflict-free, verified R7-R10), bijective XCD remap,
// fused bias+relu multi-source epilogue. pe[24].m=nullptr (R10's verified
// prep table: x converts unmasked).

typedef unsigned short ushort_t;
typedef __bf16 bf16x8 __attribute__((ext_vector_type(8)));
typedef float f32x4 __attribute__((ext_vector_type(4)));

#define SBAR()  asm volatile("s_barrier" ::: "memory")
#define LGKM0() asm volatile("s_waitcnt lgkmcnt(0)" ::: "memory")
#define VMC8()  asm volatile("s_waitcnt vmcnt(8)" ::: "memory")
#define VMC0()  asm volatile("s_waitcnt vmcnt(0)" ::: "memory")

__device__ __forceinline__ void gl_lds16(const void* g, void* l) {
  typedef __attribute__((address_space(1))) void gvoid;
  typedef __attribute__((address_space(3))) void lvoid;
  __builtin_amdgcn_global_load_lds((gvoid*)(void*)g, (lvoid*)l, 16, 0, 0);
}

__device__ __forceinline__ ushort_t f2b(float f) {
  __hip_bfloat16 h = (__hip_bfloat16)f;
  return *(ushort_t*)&h;
}

// device-scope grid barrier (persistent-kernel pattern; one-shot counter p)
__device__ __forceinline__ void gbar(int* bar, int p) {
  __threadfence();            // release: each thread's stores visible agent-wide
  __syncthreads();
  if (threadIdx.x == 0) {
    __hip_atomic_fetch_add(bar + p, 1, __ATOMIC_ACQ_REL, __HIP_MEMORY_SCOPE_AGENT);
    while (__hip_atomic_load(bar + p, __ATOMIC_ACQUIRE, __HIP_MEMORY_SCOPE_AGENT)
           < (int)gridDim.x)
      __builtin_amdgcn_s_sleep(2);
  }
  __syncthreads();
  __threadfence();            // acquire: invalidate caches before reading peers' data
}

struct PrepEnt {
  const void* w;
  const void* m;     // nullptr -> no mask
  ushort_t* o;
  int woff;
  int moff;
  int n;
  int valid;         // i >= valid -> 0
};

struct MegaArgs {
  PrepEnt pe[25];
  const ushort_t* Ap[6][4];
  const ushort_t* Bp[6][4];
  const ushort_t* bp[6][4];
  void* Cp[6];
  int* flags;
  int* bar;
};

// ---------------- fused multi-source GEMM tile (R10 verbatim, runtime) ----------------
__device__ __forceinline__ void gemm_layer(
    const ushort_t* const Asrc[4], const ushort_t* const Bsrc[4],
    const ushort_t* const bsrc[4], void* Cv,
    const int nsrc, const int K, const int N_real, const int ldc,
    const bool RELU, const bool NGUARD, const bool of32,
    ushort_t (&lds)[2][16384])
{
  __hip_bfloat16* C = (__hip_bfloat16*)Cv;
  float* Cf = (float*)Cv;

  const int tid  = threadIdx.x;
  const int lane = tid & 63;
  const int wave = tid >> 6;         // 0..3
  const int wm = (wave >> 1) * 64;   // 0,64
  const int wn = (wave & 1) * 64;    // 0,64
  const int fr = lane & 15;
  const int kg = lane >> 4;

  // XCD-aware remap (grid=512, nwg%8==0 -> bijective)
  const int lid = blockIdx.x;
  const int xcd = lid & 7, chunk = lid >> 3;   // chunk 0..63
  const int bm = (xcd * 8 + (chunk >> 3)) * 128;
  const int bn = (chunk & 7) * 128;

  // staging: linear LDS dest, inverse-swizzled global source
  const int rbase = tid >> 3;               // 0..31
  const int sg    = (tid & 7) ^ (rbase & 7);
  const size_t aoff = (size_t)(bm + rbase) * K + sg * 8;
  const size_t boff = (size_t)(bn + rbase) * K + sg * 8;
  const size_t rs32 = (size_t)32 * K;

  auto stage = [&](const ushort_t* gA, const ushort_t* gB, int buf) {
    ushort_t* base = &lds[buf][0];
    ushort_t* lA = base + wave * 512;          // A at elem 0
    ushort_t* lB = base + 8192 + wave * 512;   // B at elem 8192
    gl_lds16(gA,            lA);
    gl_lds16(gA + rs32,     lA + 2048);
    gl_lds16(gA + 2 * rs32, lA + 4096);
    gl_lds16(gA + 3 * rs32, lA + 6144);
    gl_lds16(gB,            lB);
    gl_lds16(gB + rs32,     lB + 2048);
    gl_lds16(gB + 2 * rs32, lB + 4096);
    gl_lds16(gB + 3 * rs32, lB + 6144);
  };

  // fragment read addressing (XOR-swizzled, conflict-free verified R7-R10)
  const int s0   = (kg ^ (fr & 7)) * 16;    // byte slot, ks=0; ks=1 -> ^64
  const int arow = (wm + fr) * 128;
  const int brow = 16384 + (wn + fr) * 128;

  f32x4 acc[4][4], out_acc[4][4];
#pragma unroll
  for (int i = 0; i < 4; i++)
#pragma unroll
    for (int j = 0; j < 4; j++) {
      acc[i][j] = (f32x4){0.f, 0.f, 0.f, 0.f};
      out_acc[i][j] = (f32x4){0.f, 0.f, 0.f, 0.f};
    }

  // biases preloaded (keeps vmcnt accounting in the K-loop exact)
  float bpre[4][4];
#pragma unroll
  for (int s = 0; s < 4; ++s)
#pragma unroll
    for (int ni = 0; ni < 4; ni++)
      bpre[s][ni] = (s < nsrc)
          ? (float)*(const __hip_bfloat16*)(bsrc[s] + bn + wn + ni * 16 + fr)
          : 0.0f;

  const int TPS = K >> 6;          // K-tiles per source (16 or 32)
  const int NT  = TPS * nsrc;

  // two named fragment sets (static indexing)
  bf16x8 af0[4], bf0[4], af1[4], bf1[4];

  auto rdfrag0 = [&](const char* Lb, int ks) {
    const int so = s0 ^ (ks * 64);
#pragma unroll
    for (int m = 0; m < 4; ++m) af0[m] = *(const bf16x8*)(Lb + arow + m * 2048 + so);
#pragma unroll
    for (int n = 0; n < 4; ++n) bf0[n] = *(const bf16x8*)(Lb + brow + n * 2048 + so);
  };
  auto rdfrag1 = [&](const char* Lb, int ks) {
    const int so = s0 ^ (ks * 64);
#pragma unroll
    for (int m = 0; m < 4; ++m) af1[m] = *(const bf16x8*)(Lb + arow + m * 2048 + so);
#pragma unroll
    for (int n = 0; n < 4; ++n) bf1[n] = *(const bf16x8*)(Lb + brow + n * 2048 + so);
  };
  auto mfma16_0 = [&]() {
    __builtin_amdgcn_s_setprio(1);
#pragma unroll
    for (int mi = 0; mi < 4; mi++)
#pragma unroll
      for (int ni = 0; ni < 4; ni++)
        acc[mi][ni] = __builtin_amdgcn_mfma_f32_16x16x32_bf16(
            af0[mi], bf0[ni], acc[mi][ni], 0, 0, 0);
    __builtin_amdgcn_s_setprio(0);
  };
  auto mfma16_1 = [&]() {
    __builtin_amdgcn_s_setprio(1);
#pragma unroll
    for (int mi = 0; mi < 4; mi++)
#pragma unroll
      for (int ni = 0; ni < 4; ni++)
        acc[mi][ni] = __builtin_amdgcn_mfma_f32_16x16x32_bf16(
            af1[mi], bf1[ni], acc[mi][ni], 0, 0, 0);
    __builtin_amdgcn_s_setprio(0);
  };

  // prologue: stage tiles 0,1; wait tile 0 (tile 1's 8 loads stay flying)
  stage(Asrc[0] + aoff, Bsrc[0] + boff, 0);
  stage(Asrc[0] + aoff + 64, Bsrc[0] + boff + 64, 1);   // TPS>=16 -> tile1 = src0,k=64
  VMC8();
  SBAR();
  rdfrag0((const char*)&lds[0][0], 0);

  int psrc = 0, pk0 = 128;         // next tile to stage (TPS>=16)
  int csrc = 0, ck = 0;
  int cur = 0;

  for (int t = 0; t < NT; ++t) {
    const char* Lb = (const char*)&lds[cur][0];

    // read ks=1 frags (this tile), covered by MFMA on ks=0 frags
    rdfrag1(Lb, 1);
    __builtin_amdgcn_sched_barrier(0);
    mfma16_0();

    // read-retirement fence: buf cur reusable after this barrier
    LGKM0();
    SBAR();

    ck += 64;
    const bool srcEnd = (ck == K);
    const bool more2 = (t + 2 < NT);
    if (more2) {
      stage(Asrc[psrc] + aoff + pk0, Bsrc[psrc] + boff + pk0, cur);
      pk0 += 64; if (pk0 == K) { pk0 = 0; ++psrc; }
    }

    // counted vmcnt: tile t+1's 8 loads (issued one full tile ago);
    // tile t+2's 8 stay in flight across the barrier
    if (t + 1 < NT) {
      if (more2) VMC8(); else VMC0();
      SBAR();
      rdfrag0((const char*)&lds[cur ^ 1][0], 0);
    }
    __builtin_amdgcn_sched_barrier(0);
    mfma16_1();

    // source-boundary epilogue
    if (nsrc > 1 && srcEnd) {
      float bb[4];
#pragma unroll
      for (int s = 0; s < 4; ++s)
        if (s == csrc) {
#pragma unroll
          for (int ni = 0; ni < 4; ni++) bb[ni] = bpre[s][ni];
        }
#pragma unroll
      for (int ni = 0; ni < 4; ni++)
#pragma unroll
        for (int mi = 0; mi < 4; mi++)
#pragma unroll
          for (int j = 0; j < 4; j++) {
            float v = acc[mi][ni][j] + bb[ni];
            if (RELU) v = fmaxf(v, 0.0f);
            out_acc[mi][ni][j] += v;
            acc[mi][ni][j] = 0.0f;
          }
      ck = 0; ++csrc;
    }

    cur ^= 1;
  }

  // store: C/D layout col = lane&15, row = (lane>>4)*4 + reg (verified R3)
#pragma unroll
  for (int ni = 0; ni < 4; ni++) {
    const int c = bn + wn + ni * 16 + fr;
    if (NGUARD && c >= N_real) continue;
#pragma unroll
    for (int mi = 0; mi < 4; mi++) {
      const int r0 = bm + wm + mi * 16 + kg * 4;
#pragma unroll
      for (int j = 0; j < 4; j++) {
        const size_t idx = (size_t)(r0 + j) * ldc + c;
        float v;
        if (nsrc == 1) {
          v = acc[mi][ni][j] + bpre[0][ni];
          if (RELU) v = fmaxf(v, 0.0f);
        } else {
          v = out_acc[mi][ni][j];
        }
        if (of32) Cf[idx] = v;
        else      C[idx]  = (__hip_bfloat16)v;
      }
    }
  }
}

// ---------------- persistent mega-kernel (plain launch, atomic grid barrier) ----------------
__global__ __launch_bounds__(256, 2) void meganet(MegaArgs ma) {
  __shared__ __align__(16) ushort_t lds[2][16384];
  const int tid = threadIdx.x;
  int* flags = ma.flags;
  int* bar = ma.bar;

  // ---- phase 0: dtype detection (block 0 only; verified R3) ----
  if (blockIdx.x == 0) {
    int* sdet = (int*)&lds[0][0];
    if (tid < 4) sdet[tid] = 0;
    __syncthreads();
    const ushort_t* x  = (const ushort_t*)ma.pe[24].w;   // x source
    const ushort_t* mf = (const ushort_t*)ma.pe[0].m;    // mf source
    int expout = 0, m3f80_even = 0, m3f80_odd = 0, mhi01 = 0;
    for (int k = tid; k < 2048; k += 256) {
      ushort_t w = x[k];
      int e = (w >> 7) & 0xFF;
      if (e < 96 || e > 144) expout++;
      ushort_t mw = mf[k];
      if (mw == 0x3F80) { if (k & 1) m3f80_odd++; else m3f80_even++; }
      if ((mw >> 8) == 1) mhi01++;
    }
    atomicAdd(&sdet[0], expout);
    atomicAdd(&sdet[1], m3f80_even);
    atomicAdd(&sdet[2], m3f80_odd);
    atomicAdd(&sdet[3], mhi01);
    __syncthreads();
    if (tid == 0) {
      flags[0] = (sdet[0] > 100) ? 1 : 0;
      int mmode = 0;
      if (sdet[1] > 100) mmode = 2;
      else if (sdet[2] > 100) mmode = 3;
      else if (sdet[3] > 200) mmode = 1;
      flags[1] = mmode;
    }
  }
  gbar(bar, 0);

  // ---- phase 1: masking + dtype conversion (all blocks; verified R3) ----
  {
    const bool f32 = flags[0] != 0;
    const int mmode = flags[1];
    const int stride = gridDim.x * blockDim.x;
    for (int ei = 0; ei < 25; ++ei) {
      const PrepEnt e = ma.pe[ei];
      const int nch = e.n >> 3;
      for (int ci = blockIdx.x * blockDim.x + tid; ci < nch; ci += stride) {
        const int i = ci << 3;
        ushort_t o[8] = {0, 0, 0, 0, 0, 0, 0, 0};
        if (i < e.valid) {
          ushort_t wb[8];
          if (f32) {
            const float* wp = (const float*)e.w + e.woff + i;
            float4 a = *(const float4*)wp;
            float4 b = *(const float4*)(wp + 4);
            wb[0] = f2b(a.x); wb[1] = f2b(a.y); wb[2] = f2b(a.z); wb[3] = f2b(a.w);
            wb[4] = f2b(b.x); wb[5] = f2b(b.y); wb[6] = f2b(b.z); wb[7] = f2b(b.w);
          } else {
            *(uint4*)wb = *(const uint4*)((const ushort_t*)e.w + e.woff + i);
          }
          unsigned mk = 0xFF;
          if (e.m) {
            mk = 0;
            if (mmode == 0) {
              const int4* mp = (const int4*)((const int*)e.m + e.moff + i);
              int4 a = mp[0], b = mp[1];
              mk = (a.x != 0) | ((a.y != 0) << 1) | ((a.z != 0) << 2) | ((a.w != 0) << 3) |
                   ((b.x != 0) << 4) | ((b.y != 0) << 5) | ((b.z != 0) << 6) | ((b.w != 0) << 7);
            } else if (mmode == 1) {
              const uint2 mv = *(const uint2*)((const unsigned char*)e.m + e.moff + i);
              const unsigned char* mb = (const unsigned char*)&mv;
              for (int j = 0; j < 8; j++) mk |= (mb[j] != 0) << j;
            } else if (mmode == 2) {
              uint4 mv = *(const uint4*)((const ushort_t*)e.m + e.moff + i);
              const ushort_t* ms = (const ushort_t*)&mv;
              for (int j = 0; j < 8; j++) mk |= (ms[j] != 0) << j;
            } else {
              const uint4* mp = (const uint4*)((const unsigned int*)e.m + e.moff + i);
              uint4 a = mp[0], b = mp[1];
              const unsigned* u = (const unsigned*)&a;
              const unsigned* v = (const unsigned*)&b;
              for (int j = 0; j < 4; j++) mk |= (u[j] != 0) << j;
              for (int j = 0; j < 4; j++) mk |= (v[j] != 0) << (4 + j);
            }
          }
#pragma unroll
          for (int j = 0; j < 8; j++) o[j] = ((mk >> j) & 1) ? wb[j] : (ushort_t)0;
        }
        *(uint4*)(e.o + i) = *(uint4*)o;
      }
    }
  }
  gbar(bar, 1);

  // ---- phase 2: the 6 network layers ----
  for (int li = 0; li < 6; ++li) {
    const bool last = (li == 5);
    int nsrc = 1;
    if (li >= 2 && li <= 4) nsrc = li;        // layers 2,3,4 have 2,3,4 sources
    const int K = (li == 0) ? 2048 : 1024;
    const bool of32 = last && (flags[0] != 0);
    gemm_layer(ma.Ap[li], ma.Bp[li], ma.bp[li], ma.Cp[li],
               nsrc, K, last ? 1000 : 1024, last ? 1000 : 1024,
               !last, last, of32, lds);
    if (li < 5) gbar(bar, 2 + li);
  }
}

extern "C" void kernel_launch(void* const* d_in, const int* in_sizes, int n_in,
                              void* d_out, int out_size, void* d_ws, size_t ws_size,
                              hipStream_t stream) {
  (void)out_size; (void)ws_size;
  const int Bm = 8192, DIN = 2048, H = 1024, Cn = 1000;
  const size_t HH = (size_t)H * H;

  // ---- size-signature input resolver (verified R3) ----
  struct PO { const void* p; size_t off; };
  PO x{d_in[0], 0}, Wf{d_in[0], 0}, mf{d_in[0], 0}, Wo{d_in[0], 0}, mo{d_in[0], 0};
  PO bf{d_in[0], 0}, bo{d_in[0], 0};
  PO mW[4], mM[4], mB[4], sW[6], sM[6], sB[6];
  for (int i = 0; i < 4; i++) { mW[i] = {d_in[0], 0}; mM[i] = mW[i]; mB[i] = mW[i]; }
  for (int i = 0; i < 6; i++) { sW[i] = {d_in[0], 0}; sM[i] = sW[i]; sB[i] = sW[i]; }

  {
    int c2M = 0, c1M = 0, c1k = 0, cWoMo = 0, c4 = 0, c6 = 0;
    for (int i = 0; i < n_in; i++) {
      const int s = in_sizes[i];
      const void* p = d_in[i];
      switch (s) {
        case 16777216: x = {p, 0}; break;
        case 2097152:  if (c2M++ == 0) Wf = {p, 0}; else mf = {p, 0}; break;
        case 1048576: {
          int j = c1M++;
          if (j < 4)       mW[j]      = {p, 0};
          else if (j < 8)  mM[j - 4]  = {p, 0};
          else if (j < 14) sW[j - 8]  = {p, 0};
          else if (j < 20) sM[j - 14] = {p, 0};
          break;
        }
        case 1024: {
          int j = c1k++;
          if (j == 0)      bf        = {p, 0};
          else if (j < 5)  mB[j - 1] = {p, 0};
          else if (j < 11) sB[j - 5] = {p, 0};
          break;
        }
        case 1024000: if (cWoMo++ == 0) Wo = {p, 0}; else mo = {p, 0}; break;
        case 1000: bo = {p, 0}; break;
        case 4194304:
          for (int t = 0; t < 4; t++) {
            if (c4 == 0) mW[t] = {p, t * HH}; else mM[t] = {p, t * HH};
          }
          c4++; break;
        case 6291456:
          for (int t = 0; t < 6; t++) {
            if (c6 == 0) sW[t] = {p, t * HH}; else sM[t] = {p, t * HH};
          }
          c6++; break;
        case 4096:
          for (int t = 0; t < 4; t++) mB[t] = {p, (size_t)t * H};
          break;
        case 6144:
          for (int t = 0; t < 6; t++) sB[t] = {p, (size_t)t * H};
          break;
        default: break;
      }
    }
  }

  // ---- workspace layout (ushort units) ----
  ushort_t* wsp = (ushort_t*)d_ws;
  size_t off = 0;
  int* bar = (int*)wsp; off += 64;            // 32 ints, zeroed each launch
  int* flags = (int*)(wsp + off); off += 32;
  ushort_t* xc = wsp + off; off += (size_t)Bm * DIN;
  __hip_bfloat16* r[5];
  for (int i = 0; i < 5; i++) { r[i] = (__hip_bfloat16*)(wsp + off); off += (size_t)Bm * H; }
  ushort_t* wWf = wsp + off; off += (size_t)H * DIN;
  ushort_t* wMain[4];
  for (int i = 0; i < 4; i++) { wMain[i] = wsp + off; off += HH; }
  ushort_t* wSkip[6];
  for (int k = 0; k < 6; k++) { wSkip[k] = wsp + off; off += HH; }
  ushort_t* wWo = wsp + off; off += (size_t)1024 * 1024;  // zero-padded to 1024 rows
  ushort_t* cbf_ = wsp + off; off += 1024;
  ushort_t* cmB[4];
  for (int i = 0; i < 4; i++) { cmB[i] = wsp + off; off += 1024; }
  ushort_t* csB[6];
  for (int k = 0; k < 6; k++) { csB[k] = wsp + off; off += 1024; }
  ushort_t* cbo = wsp + off; off += 1024;                 // tail 1000..1023 zeroed

  // ---- mega-args ----
  MegaArgs ma;
  ma.flags = flags;
  ma.bar = bar;
  ma.pe[0]  = { Wf.p, mf.p, wWf, (int)Wf.off, (int)mf.off, H * DIN, H * DIN };
  for (int i = 0; i < 4; i++)
    ma.pe[1 + i] = { mW[i].p, mM[i].p, wMain[i], (int)mW[i].off, (int)mM[i].off, (int)HH, (int)HH };
  for (int k = 0; k < 6; k++)
    ma.pe[5 + k] = { sW[k].p, sM[k].p, wSkip[k], (int)sW[k].off, (int)sM[k].off, (int)HH, (int)HH };
  ma.pe[11] = { Wo.p, mo.p, wWo, (int)Wo.off, (int)mo.off, 1024 * 1024, Cn * H };
  ma.pe[12] = { bf.p, nullptr, cbf_, (int)bf.off, 0, H, H };
  for (int i = 0; i < 4; i++)
    ma.pe[13 + i] = { mB[i].p, nullptr, cmB[i], (int)mB[i].off, 0, H, H };
  for (int k = 0; k < 6; k++)
    ma.pe[17 + k] = { sB[k].p, nullptr, csB[k], (int)sB[k].off, 0, H, H };
  ma.pe[23] = { bo.p, nullptr, cbo, (int)bo.off, 0, 1024, Cn };
  // x conversion: NO MASK (R10's verified prep table; detect reads mf via pe[0].m)
  ma.pe[24] = { x.p, nullptr, xc, (int)x.off, 0, Bm * DIN, Bm * DIN };

  // layer source tables (unused slots duplicate source 0 — never dereferenced
  // beyond nsrc, but kept valid for safety)
  for (int li = 0; li < 6; ++li)
    for (int s = 0; s < 4; ++s) { ma.Ap[li][s] = xc; ma.Bp[li][s] = wWf; ma.bp[li][s] = cbf_; }

  ma.Ap[0][0] = xc;                 ma.Bp[0][0] = wWf;      ma.bp[0][0] = cbf_;
  ma.Ap[1][0] = (ushort_t*)r[0];    ma.Bp[1][0] = wMain[0]; ma.bp[1][0] = cmB[0];
  ma.Ap[2][0] = (ushort_t*)r[1];    ma.Bp[2][0] = wMain[1]; ma.bp[2][0] = cmB[1];
  ma.Ap[2][1] = (ushort_t*)r[0];    ma.Bp[2][1] = wSkip[0]; ma.bp[2][1] = csB[0];
  ma.Ap[3][0] = (ushort_t*)r[2];    ma.Bp[3][0] = wMain[2]; ma.bp[3][0] = cmB[2];
  ma.Ap[3][1] = (ushort_t*)r[0];    ma.Bp[3][1] = wSkip[1]; ma.bp[3][1] = csB[1];
  ma.Ap[3][2] = (ushort_t*)r[1];    ma.Bp[3][2] = wSkip[2]; ma.bp[3][2] = csB[2];
  ma.Ap[4][0] = (ushort_t*)r[3];    ma.Bp[4][0] = wMain[3]; ma.bp[4][0] = cmB[3];
  ma.Ap[4][1] = (ushort_t*)r[0];    ma.Bp[4][1] = wSkip[3]; ma.bp[4][1] = csB[3];
  ma.Ap[4][2] = (ushort_t*)r[1];    ma.Bp[4][2] = wSkip[4]; ma.bp[4][2] = csB[4];
  ma.Ap[4][3] = (ushort_t*)r[2];    ma.Bp[4][3] = wSkip[5]; ma.bp[4][3] = csB[5];
  ma.Ap[5][0] = (ushort_t*)r[4];    ma.Bp[5][0] = wWo;      ma.bp[5][0] = cbo;

  ma.Cp[0] = r[0]; ma.Cp[1] = r[1]; ma.Cp[2] = r[2];
  ma.Cp[3] = r[3]; ma.Cp[4] = r[4]; ma.Cp[5] = d_out;

  // ---- zero the barrier counters, then one plain (graph-capturable) launch ----
  hipMemsetAsync(d_ws, 0, 128, stream);
  meganet<<<dim3(512), dim3(256), 0, stream>>>(ma);
}

// Round 9
// 1797.159 us; speedup vs baseline: 1.0231x; 1.0231x over previous
//
#include <hip/hip_runtime.h>
#include <hip/hip_bf16.h>
#include <stdint.h>

// MaskedDeepDAN on MI355X (gfx950). B=8192, D_IN=2048, H=1024, C=1000.
// R15: R14's fused kernel was correct but 3.5x slow from rule-#20 scratch
// spill: runtime-li loop + runtime-indexed pointer arrays (ma.Ap[li][s],
// Asrc[psrc], runtime nsrc) -> ~1.5KB state spilled to scratch, re-read per
// tile (+160MB FETCH = measured delta; MFMA-busy conserved at ~90us-equiv).
// Fix: ALL indices compile-time. gemm_layer restored to R10's verbatim
// template<NSRC,RELU,NGUARD> (GemmArgs by value -> kernarg s_load, SGPRs),
// SIX explicit call sites, no runtime layer loop. Detect/prep/gbar/memset
// carried bit-for-bit from R14 (correctness proven: passed absmax 9.8e-4).
// Fused phases: 0 detect (block 0) | 1 prep | 2..7 six GEMM layers, with
// hand-rolled device-scope grid barrier between (hipLaunchCooperativeKernel
// is NOT graph-capturable - R12/R13 lesson; plain launch + atomic bar is).
// GEMM = R10's verified 515us structure: 128x128 tile BK=64, 4 waves 2x2,
// half-tile-pipelined frags, 2 barriers/tile, counted vmcnt(8), XOR-swizzled
// staging/reads (conflict-free), bijective XCD remap, fused bias+relu
// multi-source epilogue. Grid 512x256, launch_bounds(256,2): 2 blocks/CU
// co-resident (LDS 64KB) -> barrier cannot deadlock (R14 empirically ran).

typedef unsigned short ushort_t;
typedef __bf16 bf16x8 __attribute__((ext_vector_type(8)));
typedef float f32x4 __attribute__((ext_vector_type(4)));

#define SBAR()  asm volatile("s_barrier" ::: "memory")
#define LGKM0() asm volatile("s_waitcnt lgkmcnt(0)" ::: "memory")
#define VMC8()  asm volatile("s_waitcnt vmcnt(8)" ::: "memory")
#define VMC0()  asm volatile("s_waitcnt vmcnt(0)" ::: "memory")

__device__ __forceinline__ void gl_lds16(const void* g, void* l) {
  typedef __attribute__((address_space(1))) void gvoid;
  typedef __attribute__((address_space(3))) void lvoid;
  __builtin_amdgcn_global_load_lds((gvoid*)(void*)g, (lvoid*)l, 16, 0, 0);
}

__device__ __forceinline__ ushort_t f2b(float f) {
  __hip_bfloat16 h = (__hip_bfloat16)f;
  return *(ushort_t*)&h;
}

// device-scope grid barrier (persistent-kernel pattern; one-shot counter p)
__device__ __forceinline__ void gbar(int* bar, int p) {
  __threadfence();            // release: stores visible agent-wide
  __syncthreads();
  if (threadIdx.x == 0) {
    __hip_atomic_fetch_add(bar + p, 1, __ATOMIC_ACQ_REL, __HIP_MEMORY_SCOPE_AGENT);
    while (__hip_atomic_load(bar + p, __ATOMIC_ACQUIRE, __HIP_MEMORY_SCOPE_AGENT)
           < (int)gridDim.x)
      __builtin_amdgcn_s_sleep(2);
  }
  __syncthreads();
  __threadfence();            // acquire: invalidate caches before reading peers' data
}

struct PrepEnt {
  const void* w;
  const void* m;     // nullptr -> no mask
  ushort_t* o;
  int woff;
  int moff;
  int n;
  int valid;         // i >= valid -> 0
};

struct GemmSrc { const ushort_t* A; const ushort_t* B; const ushort_t* bias; };
struct GemmArgs { GemmSrc s[4]; };

struct MegaArgs {
  PrepEnt pe[25];
  GemmArgs a0, a1, a2, a3, a4, ao;   // named per-layer args (literal access)
  void* C0; void* C1; void* C2; void* C3; void* C4; void* C5;
  int* flags;
  int* bar;
};

// ---------------- fused multi-source GEMM tile (R10 verbatim) ----------------
template <int NSRC, bool RELU, bool NGUARD>
__device__ __forceinline__ void gemm_layer(
    const GemmArgs args, void* Cv, const int* of32flag,
    const int K, const int N_real, const int ldc,
    ushort_t (&lds)[2][16384])
{
  const bool of32 = (of32flag != nullptr) && (of32flag[0] != 0);
  __hip_bfloat16* C = (__hip_bfloat16*)Cv;
  float* Cf = (float*)Cv;

  const int tid  = threadIdx.x;
  const int lane = tid & 63;
  const int wave = tid >> 6;         // 0..3
  const int wm = (wave >> 1) * 64;   // 0,64
  const int wn = (wave & 1) * 64;    // 0,64
  const int fr = lane & 15;
  const int kg = lane >> 4;

  // XCD-aware remap (grid=512, nwg%8==0 -> bijective)
  const int lid = blockIdx.x;
  const int xcd = lid & 7, chunk = lid >> 3;   // chunk 0..63
  const int bm = (xcd * 8 + (chunk >> 3)) * 128;
  const int bn = (chunk & 7) * 128;

  // staging: linear LDS dest, inverse-swizzled global source
  const int rbase = tid >> 3;               // 0..31
  const int sg    = (tid & 7) ^ (rbase & 7);
  const size_t aoff = (size_t)(bm + rbase) * K + sg * 8;
  const size_t boff = (size_t)(bn + rbase) * K + sg * 8;
  const size_t rs32 = (size_t)32 * K;

  auto stage = [&](const ushort_t* gA, const ushort_t* gB, int buf) {
    ushort_t* base = &lds[buf][0];
    ushort_t* lA = base + wave * 512;          // A at elem 0
    ushort_t* lB = base + 8192 + wave * 512;   // B at elem 8192
    gl_lds16(gA,            lA);
    gl_lds16(gA + rs32,     lA + 2048);
    gl_lds16(gA + 2 * rs32, lA + 4096);
    gl_lds16(gA + 3 * rs32, lA + 6144);
    gl_lds16(gB,            lB);
    gl_lds16(gB + rs32,     lB + 2048);
    gl_lds16(gB + 2 * rs32, lB + 4096);
    gl_lds16(gB + 3 * rs32, lB + 6144);
  };

  // fragment read addressing (XOR-swizzled, conflict-free verified R7-R10)
  const int s0   = (kg ^ (fr & 7)) * 16;    // byte slot, ks=0; ks=1 -> ^64
  const int arow = (wm + fr) * 128;
  const int brow = 16384 + (wn + fr) * 128;

  f32x4 acc[4][4], out_acc[4][4];
#pragma unroll
  for (int i = 0; i < 4; i++)
#pragma unroll
    for (int j = 0; j < 4; j++) {
      acc[i][j] = (f32x4){0.f, 0.f, 0.f, 0.f};
      if (NSRC > 1) out_acc[i][j] = (f32x4){0.f, 0.f, 0.f, 0.f};
    }

  // biases preloaded (keeps vmcnt accounting in the K-loop exact)
  float bpre[NSRC][4];
#pragma unroll
  for (int s = 0; s < NSRC; ++s)
#pragma unroll
    for (int ni = 0; ni < 4; ni++)
      bpre[s][ni] = (float)*(const __hip_bfloat16*)
          (args.s[s].bias + bn + wn + ni * 16 + fr);

  const int TPS = K >> 6;          // K-tiles per source (16 or 32)
  const int NT  = TPS * NSRC;

  // two named fragment sets (static indexing)
  bf16x8 af0[4], bf0[4], af1[4], bf1[4];

  auto rdfrag0 = [&](const char* Lb, int ks) {
    const int so = s0 ^ (ks * 64);
#pragma unroll
    for (int m = 0; m < 4; ++m) af0[m] = *(const bf16x8*)(Lb + arow + m * 2048 + so);
#pragma unroll
    for (int n = 0; n < 4; ++n) bf0[n] = *(const bf16x8*)(Lb + brow + n * 2048 + so);
  };
  auto rdfrag1 = [&](const char* Lb, int ks) {
    const int so = s0 ^ (ks * 64);
#pragma unroll
    for (int m = 0; m < 4; ++m) af1[m] = *(const bf16x8*)(Lb + arow + m * 2048 + so);
#pragma unroll
    for (int n = 0; n < 4; ++n) bf1[n] = *(const bf16x8*)(Lb + brow + n * 2048 + so);
  };
  auto mfma16_0 = [&]() {
    __builtin_amdgcn_s_setprio(1);
#pragma unroll
    for (int mi = 0; mi < 4; mi++)
#pragma unroll
      for (int ni = 0; ni < 4; ni++)
        acc[mi][ni] = __builtin_amdgcn_mfma_f32_16x16x32_bf16(
            af0[mi], bf0[ni], acc[mi][ni], 0, 0, 0);
    __builtin_amdgcn_s_setprio(0);
  };
  auto mfma16_1 = [&]() {
    __builtin_amdgcn_s_setprio(1);
#pragma unroll
    for (int mi = 0; mi < 4; mi++)
#pragma unroll
      for (int ni = 0; ni < 4; ni++)
        acc[mi][ni] = __builtin_amdgcn_mfma_f32_16x16x32_bf16(
            af1[mi], bf1[ni], acc[mi][ni], 0, 0, 0);
    __builtin_amdgcn_s_setprio(0);
  };

  // prologue: stage tiles 0,1; wait tile 0 (tile 1's 8 loads stay flying)
  stage(args.s[0].A + aoff, args.s[0].B + boff, 0);
  {
    const int s1 = 1 / TPS, k1 = (1 % TPS) * 64;
    stage(args.s[s1].A + aoff + k1, args.s[s1].B + boff + k1, 1);
  }
  VMC8();
  SBAR();
  rdfrag0((const char*)&lds[0][0], 0);

  int psrc = 2 / TPS, pk0 = (2 % TPS) * 64;  // next tile to stage
  int csrc = 0, ck = 0;
  int cur = 0;

  for (int t = 0; t < NT; ++t) {
    const char* Lb = (const char*)&lds[cur][0];

    // read ks=1 frags (this tile), covered by MFMA on ks=0 frags
    rdfrag1(Lb, 1);
    __builtin_amdgcn_sched_barrier(0);
    mfma16_0();

    // read-retirement fence: buf cur reusable after this barrier
    LGKM0();
    SBAR();

    ck += 64;
    const bool srcEnd = (ck == K);
    const bool more2 = (t + 2 < NT);
    if (more2) {
      stage(args.s[psrc].A + aoff + pk0, args.s[psrc].B + boff + pk0, cur);
      pk0 += 64; if (pk0 == K) { pk0 = 0; ++psrc; }
    }

    // counted vmcnt: tile t+1's 8 loads (issued one full tile ago);
    // tile t+2's 8 stay in flight across the barrier
    if (t + 1 < NT) {
      if (more2) VMC8(); else VMC0();
      SBAR();
      rdfrag0((const char*)&lds[cur ^ 1][0], 0);
    }
    __builtin_amdgcn_sched_barrier(0);
    mfma16_1();

    // source-boundary epilogue
    if (NSRC > 1 && srcEnd) {
      float bb[4];
#pragma unroll
      for (int s = 0; s < NSRC; ++s)
        if (s == csrc) {
#pragma unroll
          for (int ni = 0; ni < 4; ni++) bb[ni] = bpre[s][ni];
        }
#pragma unroll
      for (int ni = 0; ni < 4; ni++)
#pragma unroll
        for (int mi = 0; mi < 4; mi++)
#pragma unroll
          for (int j = 0; j < 4; j++) {
            float v = acc[mi][ni][j] + bb[ni];
            if (RELU) v = fmaxf(v, 0.0f);
            out_acc[mi][ni][j] += v;
            acc[mi][ni][j] = 0.0f;
          }
      ck = 0; ++csrc;
    }

    cur ^= 1;
  }

  // store: C/D layout col = lane&15, row = (lane>>4)*4 + reg (verified R3)
#pragma unroll
  for (int ni = 0; ni < 4; ni++) {
    const int c = bn + wn + ni * 16 + fr;
    if (NGUARD && c >= N_real) continue;
#pragma unroll
    for (int mi = 0; mi < 4; mi++) {
      const int r0 = bm + wm + mi * 16 + kg * 4;
#pragma unroll
      for (int j = 0; j < 4; j++) {
        const size_t idx = (size_t)(r0 + j) * ldc + c;
        float v;
        if (NSRC == 1) {
          v = acc[mi][ni][j] + bpre[0][ni];
          if (RELU) v = fmaxf(v, 0.0f);
        } else {
          v = out_acc[mi][ni][j];
        }
        if (of32) Cf[idx] = v;
        else      C[idx]  = (__hip_bfloat16)v;
      }
    }
  }
}

// ---------------- persistent mega-kernel (plain launch, atomic grid barrier) ----------------
__global__ __launch_bounds__(256, 2) void meganet(MegaArgs ma) {
  __shared__ __align__(16) ushort_t lds[2][16384];
  const int tid = threadIdx.x;
  int* flags = ma.flags;
  int* bar = ma.bar;

  // ---- phase 0: dtype detection (block 0 only; verified R3) ----
  if (blockIdx.x == 0) {
    int* sdet = (int*)&lds[0][0];
    if (tid < 4) sdet[tid] = 0;
    __syncthreads();
    const ushort_t* x  = (const ushort_t*)ma.pe[24].w;   // x source
    const ushort_t* mf = (const ushort_t*)ma.pe[0].m;    // mf source
    int expout = 0, m3f80_even = 0, m3f80_odd = 0, mhi01 = 0;
    for (int k = tid; k < 2048; k += 256) {
      ushort_t w = x[k];
      int e = (w >> 7) & 0xFF;
      if (e < 96 || e > 144) expout++;
      ushort_t mw = mf[k];
      if (mw == 0x3F80) { if (k & 1) m3f80_odd++; else m3f80_even++; }
      if ((mw >> 8) == 1) mhi01++;
    }
    atomicAdd(&sdet[0], expout);
    atomicAdd(&sdet[1], m3f80_even);
    atomicAdd(&sdet[2], m3f80_odd);
    atomicAdd(&sdet[3], mhi01);
    __syncthreads();
    if (tid == 0) {
      flags[0] = (sdet[0] > 100) ? 1 : 0;
      int mmode = 0;
      if (sdet[1] > 100) mmode = 2;
      else if (sdet[2] > 100) mmode = 3;
      else if (sdet[3] > 200) mmode = 1;
      flags[1] = mmode;
    }
  }
  gbar(bar, 0);

  // ---- phase 1: masking + dtype conversion (all blocks; verified R3) ----
  {
    const bool f32 = flags[0] != 0;
    const int mmode = flags[1];
    const int stride = gridDim.x * blockDim.x;
    for (int ei = 0; ei < 25; ++ei) {
      const PrepEnt e = ma.pe[ei];     // uniform index -> kernarg s_load
      const int nch = e.n >> 3;
      for (int ci = blockIdx.x * blockDim.x + tid; ci < nch; ci += stride) {
        const int i = ci << 3;
        ushort_t o[8] = {0, 0, 0, 0, 0, 0, 0, 0};
        if (i < e.valid) {
          ushort_t wb[8];
          if (f32) {
            const float* wp = (const float*)e.w + e.woff + i;
            float4 a = *(const float4*)wp;
            float4 b = *(const float4*)(wp + 4);
            wb[0] = f2b(a.x); wb[1] = f2b(a.y); wb[2] = f2b(a.z); wb[3] = f2b(a.w);
            wb[4] = f2b(b.x); wb[5] = f2b(b.y); wb[6] = f2b(b.z); wb[7] = f2b(b.w);
          } else {
            *(uint4*)wb = *(const uint4*)((const ushort_t*)e.w + e.woff + i);
          }
          unsigned mk = 0xFF;
          if (e.m) {
            mk = 0;
            if (mmode == 0) {
              const int4* mp = (const int4*)((const int*)e.m + e.moff + i);
              int4 a = mp[0], b = mp[1];
              mk = (a.x != 0) | ((a.y != 0) << 1) | ((a.z != 0) << 2) | ((a.w != 0) << 3) |
                   ((b.x != 0) << 4) | ((b.y != 0) << 5) | ((b.z != 0) << 6) | ((b.w != 0) << 7);
            } else if (mmode == 1) {
              const uint2 mv = *(const uint2*)((const unsigned char*)e.m + e.moff + i);
              const unsigned char* mb = (const unsigned char*)&mv;
              for (int j = 0; j < 8; j++) mk |= (mb[j] != 0) << j;
            } else if (mmode == 2) {
              uint4 mv = *(const uint4*)((const ushort_t*)e.m + e.moff + i);
              const ushort_t* ms = (const ushort_t*)&mv;
              for (int j = 0; j < 8; j++) mk |= (ms[j] != 0) << j;
            } else {
              const uint4* mp = (const uint4*)((const unsigned int*)e.m + e.moff + i);
              uint4 a = mp[0], b = mp[1];
              const unsigned* u = (const unsigned*)&a;
              const unsigned* v = (const unsigned*)&b;
              for (int j = 0; j < 4; j++) mk |= (u[j] != 0) << j;
              for (int j = 0; j < 4; j++) mk |= (v[j] != 0) << (4 + j);
            }
          }
#pragma unroll
          for (int j = 0; j < 8; j++) o[j] = ((mk >> j) & 1) ? wb[j] : (ushort_t)0;
        }
        *(uint4*)(e.o + i) = *(uint4*)o;
      }
    }
  }
  gbar(bar, 1);

  // ---- phase 2: the 6 network layers (compile-time instantiations) ----
  gemm_layer<1, true,  false>(ma.a0, ma.C0, nullptr, 2048, 1024, 1024, lds);
  gbar(bar, 2);
  gemm_layer<1, true,  false>(ma.a1, ma.C1, nullptr, 1024, 1024, 1024, lds);
  gbar(bar, 3);
  gemm_layer<2, true,  false>(ma.a2, ma.C2, nullptr, 1024, 1024, 1024, lds);
  gbar(bar, 4);
  gemm_layer<3, true,  false>(ma.a3, ma.C3, nullptr, 1024, 1024, 1024, lds);
  gbar(bar, 5);
  gemm_layer<4, true,  false>(ma.a4, ma.C4, nullptr, 1024, 1024, 1024, lds);
  gbar(bar, 6);
  gemm_layer<1, false, true >(ma.ao, ma.C5, flags,   1024, 1000, 1000, lds);
}

extern "C" void kernel_launch(void* const* d_in, const int* in_sizes, int n_in,
                              void* d_out, int out_size, void* d_ws, size_t ws_size,
                              hipStream_t stream) {
  (void)out_size; (void)ws_size;
  const int Bm = 8192, DIN = 2048, H = 1024, Cn = 1000;
  const size_t HH = (size_t)H * H;

  // ---- size-signature input resolver (verified R3) ----
  struct PO { const void* p; size_t off; };
  PO x{d_in[0], 0}, Wf{d_in[0], 0}, mf{d_in[0], 0}, Wo{d_in[0], 0}, mo{d_in[0], 0};
  PO bf{d_in[0], 0}, bo{d_in[0], 0};
  PO mW[4], mM[4], mB[4], sW[6], sM[6], sB[6];
  for (int i = 0; i < 4; i++) { mW[i] = {d_in[0], 0}; mM[i] = mW[i]; mB[i] = mW[i]; }
  for (int i = 0; i < 6; i++) { sW[i] = {d_in[0], 0}; sM[i] = sW[i]; sB[i] = sW[i]; }

  {
    int c2M = 0, c1M = 0, c1k = 0, cWoMo = 0, c4 = 0, c6 = 0;
    for (int i = 0; i < n_in; i++) {
      const int s = in_sizes[i];
      const void* p = d_in[i];
      switch (s) {
        case 16777216: x = {p, 0}; break;
        case 2097152:  if (c2M++ == 0) Wf = {p, 0}; else mf = {p, 0}; break;
        case 1048576: {
          int j = c1M++;
          if (j < 4)       mW[j]      = {p, 0};
          else if (j < 8)  mM[j - 4]  = {p, 0};
          else if (j < 14) sW[j - 8]  = {p, 0};
          else if (j < 20) sM[j - 14] = {p, 0};
          break;
        }
        case 1024: {
          int j = c1k++;
          if (j == 0)      bf        = {p, 0};
          else if (j < 5)  mB[j - 1] = {p, 0};
          else if (j < 11) sB[j - 5] = {p, 0};
          break;
        }
        case 1024000: if (cWoMo++ == 0) Wo = {p, 0}; else mo = {p, 0}; break;
        case 1000: bo = {p, 0}; break;
        case 4194304:
          for (int t = 0; t < 4; t++) {
            if (c4 == 0) mW[t] = {p, t * HH}; else mM[t] = {p, t * HH};
          }
          c4++; break;
        case 6291456:
          for (int t = 0; t < 6; t++) {
            if (c6 == 0) sW[t] = {p, t * HH}; else sM[t] = {p, t * HH};
          }
          c6++; break;
        case 4096:
          for (int t = 0; t < 4; t++) mB[t] = {p, (size_t)t * H};
          break;
        case 6144:
          for (int t = 0; t < 6; t++) sB[t] = {p, (size_t)t * H};
          break;
        default: break;
      }
    }
  }

  // ---- workspace layout (ushort units) ----
  ushort_t* wsp = (ushort_t*)d_ws;
  size_t off = 0;
  int* bar = (int*)wsp; off += 64;            // 32 ints, zeroed each launch
  int* flags = (int*)(wsp + off); off += 32;
  ushort_t* xc = wsp + off; off += (size_t)Bm * DIN;
  __hip_bfloat16* r[5];
  for (int i = 0; i < 5; i++) { r[i] = (__hip_bfloat16*)(wsp + off); off += (size_t)Bm * H; }
  ushort_t* wWf = wsp + off; off += (size_t)H * DIN;
  ushort_t* wMain[4];
  for (int i = 0; i < 4; i++) { wMain[i] = wsp + off; off += HH; }
  ushort_t* wSkip[6];
  for (int k = 0; k < 6; k++) { wSkip[k] = wsp + off; off += HH; }
  ushort_t* wWo = wsp + off; off += (size_t)1024 * 1024;  // zero-padded to 1024 rows
  ushort_t* cbf_ = wsp + off; off += 1024;
  ushort_t* cmB[4];
  for (int i = 0; i < 4; i++) { cmB[i] = wsp + off; off += 1024; }
  ushort_t* csB[6];
  for (int k = 0; k < 6; k++) { csB[k] = wsp + off; off += 1024; }
  ushort_t* cbo = wsp + off; off += 1024;                 // tail 1000..1023 zeroed

  // ---- mega-args ----
  MegaArgs ma;
  ma.flags = flags;
  ma.bar = bar;
  ma.pe[0]  = { Wf.p, mf.p, wWf, (int)Wf.off, (int)mf.off, H * DIN, H * DIN };
  for (int i = 0; i < 4; i++)
    ma.pe[1 + i] = { mW[i].p, mM[i].p, wMain[i], (int)mW[i].off, (int)mM[i].off, (int)HH, (int)HH };
  for (int k = 0; k < 6; k++)
    ma.pe[5 + k] = { sW[k].p, sM[k].p, wSkip[k], (int)sW[k].off, (int)sM[k].off, (int)HH, (int)HH };
  ma.pe[11] = { Wo.p, mo.p, wWo, (int)Wo.off, (int)mo.off, 1024 * 1024, Cn * H };
  ma.pe[12] = { bf.p, nullptr, cbf_, (int)bf.off, 0, H, H };
  for (int i = 0; i < 4; i++)
    ma.pe[13 + i] = { mB[i].p, nullptr, cmB[i], (int)mB[i].off, 0, H, H };
  for (int k = 0; k < 6; k++)
    ma.pe[17 + k] = { sB[k].p, nullptr, csB[k], (int)sB[k].off, 0, H, H };
  ma.pe[23] = { bo.p, nullptr, cbo, (int)bo.off, 0, 1024, Cn };
  // x conversion: NO MASK (R10's verified prep table; detect reads mf via pe[0].m)
  ma.pe[24] = { x.p, nullptr, xc, (int)x.off, 0, Bm * DIN, Bm * DIN };

  // per-layer GEMM args (unused slots = source 0, never dereferenced beyond NSRC)
  ma.a0.s[0] = { xc, wWf, cbf_ };
  for (int s = 1; s < 4; ++s) ma.a0.s[s] = ma.a0.s[0];
  ma.a1.s[0] = { (ushort_t*)r[0], wMain[0], cmB[0] };
  for (int s = 1; s < 4; ++s) ma.a1.s[s] = ma.a1.s[0];
  ma.a2.s[0] = { (ushort_t*)r[1], wMain[1], cmB[1] };
  ma.a2.s[1] = { (ushort_t*)r[0], wSkip[0], csB[0] };
  ma.a2.s[2] = ma.a2.s[0]; ma.a2.s[3] = ma.a2.s[0];
  ma.a3.s[0] = { (ushort_t*)r[2], wMain[2], cmB[2] };
  ma.a3.s[1] = { (ushort_t*)r[0], wSkip[1], csB[1] };
  ma.a3.s[2] = { (ushort_t*)r[1], wSkip[2], csB[2] };
  ma.a3.s[3] = ma.a3.s[0];
  ma.a4.s[0] = { (ushort_t*)r[3], wMain[3], cmB[3] };
  ma.a4.s[1] = { (ushort_t*)r[0], wSkip[3], csB[3] };
  ma.a4.s[2] = { (ushort_t*)r[1], wSkip[4], csB[4] };
  ma.a4.s[3] = { (ushort_t*)r[2], wSkip[5], csB[5] };
  ma.ao.s[0] = { (ushort_t*)r[4], wWo, cbo };
  for (int s = 1; s < 4; ++s) ma.ao.s[s] = ma.ao.s[0];

  ma.C0 = r[0]; ma.C1 = r[1]; ma.C2 = r[2];
  ma.C3 = r[3]; ma.C4 = r[4]; ma.C5 = d_out;

  // ---- zero the barrier counters, then one plain (graph-capturable) launch ----
  hipMemsetAsync(d_ws, 0, 128, stream);
  meganet<<<dim3(512), dim3(256), 0, stream>>>(ma);
}

// Round 10
// 1049.158 us; speedup vs baseline: 1.7526x; 1.7130x over previous
//
#include <hip/hip_runtime.h>
#include <hip/hip_bf16.h>
#include <stdint.h>

// MaskedDeepDAN on MI355X (gfx950). B=8192, D_IN=2048, H=1024, C=1000.
// R16: R14==R15 (1797us, FETCH 352MB, MFMA-busy conserved ~91us) killed the
// scratch theory -> the ~1200us residual is FENCE COST, common to both:
// (a) per-THREAD __threadfence at each phase boundary (131072 threads x 2 x
// 7 barriers -> ~28K L2 writeback/invalidate walks serializing per XCD), and
// (b) the spin polled with ATOMIC_ACQUIRE -> EVERY POLL of 512 spinners
// re-invalidates its XCD L2 for the whole skew window (also explains FETCH
// inflation + both pipes idle). Fix (only gbar changes vs R15):
//   - __syncthreads() already drains stores to L2 (vmcnt(0) before s_barrier)
//   - ONE __threadfence() per BLOCK (thread 0) as release (every CU hosts
//     fencing blocks -> all L1s covered; 64 blocks/XCD -> all L2s covered)
//   - spin with ATOMIC_RELAXED (agent-scope load reads coherent value, NO
//     per-poll invalidate) + s_sleep(8)
//   - ONE __threadfence() per block after exit as acquire (fence-fence sync)
// => 512 fence-pairs per barrier instead of 131072, zero per-poll invs.
// Everything else bit-identical to R15 (passed, absmax 9.8e-4): fused
// detect/prep/6-layer GEMM, compile-time template instantiations, R10's
// verified 128x128 BK=64 half-tile-pipelined GEMM, XOR swizzle, XCD remap,
// counted vmcnt(8), plain launch (graph-capturable) + atomic grid barrier.

typedef unsigned short ushort_t;
typedef __bf16 bf16x8 __attribute__((ext_vector_type(8)));
typedef float f32x4 __attribute__((ext_vector_type(4)));

#define SBAR()  asm volatile("s_barrier" ::: "memory")
#define LGKM0() asm volatile("s_waitcnt lgkmcnt(0)" ::: "memory")
#define VMC8()  asm volatile("s_waitcnt vmcnt(8)" ::: "memory")
#define VMC0()  asm volatile("s_waitcnt vmcnt(0)" ::: "memory")

__device__ __forceinline__ void gl_lds16(const void* g, void* l) {
  typedef __attribute__((address_space(1))) void gvoid;
  typedef __attribute__((address_space(3))) void lvoid;
  __builtin_amdgcn_global_load_lds((gvoid*)(void*)g, (lvoid*)l, 16, 0, 0);
}

__device__ __forceinline__ ushort_t f2b(float f) {
  __hip_bfloat16 h = (__hip_bfloat16)f;
  return *(ushort_t*)&h;
}

// device-scope grid barrier, O(blocks) fence cost (R16)
__device__ __forceinline__ void gbar(int* bar, int p) {
  __syncthreads();   // drains each wave's vmcnt/lgkm (stores in L2) + block barrier
  if (threadIdx.x == 0) {
    __threadfence(); // release ONCE per block: L2 writeback (covers all waves' lines)
    __hip_atomic_fetch_add(bar + p, 1, __ATOMIC_RELEASE, __HIP_MEMORY_SCOPE_AGENT);
    while (__hip_atomic_load(bar + p, __ATOMIC_RELAXED, __HIP_MEMORY_SCOPE_AGENT)
           < (int)gridDim.x)
      __builtin_amdgcn_s_sleep(8);
    __threadfence(); // acquire ONCE per block: invalidate L1/L2 before reading peers
  }
  __syncthreads();
}

struct PrepEnt {
  const void* w;
  const void* m;     // nullptr -> no mask
  ushort_t* o;
  int woff;
  int moff;
  int n;
  int valid;         // i >= valid -> 0
};

struct GemmSrc { const ushort_t* A; const ushort_t* B; const ushort_t* bias; };
struct GemmArgs { GemmSrc s[4]; };

struct MegaArgs {
  PrepEnt pe[25];
  GemmArgs a0, a1, a2, a3, a4, ao;   // named per-layer args (literal access)
  void* C0; void* C1; void* C2; void* C3; void* C4; void* C5;
  int* flags;
  int* bar;
};

// ---------------- fused multi-source GEMM tile (R10 verbatim) ----------------
template <int NSRC, bool RELU, bool NGUARD>
__device__ __forceinline__ void gemm_layer(
    const GemmArgs args, void* Cv, const int* of32flag,
    const int K, const int N_real, const int ldc,
    ushort_t (&lds)[2][16384])
{
  const bool of32 = (of32flag != nullptr) && (of32flag[0] != 0);
  __hip_bfloat16* C = (__hip_bfloat16*)Cv;
  float* Cf = (float*)Cv;

  const int tid  = threadIdx.x;
  const int lane = tid & 63;
  const int wave = tid >> 6;         // 0..3
  const int wm = (wave >> 1) * 64;   // 0,64
  const int wn = (wave & 1) * 64;    // 0,64
  const int fr = lane & 15;
  const int kg = lane >> 4;

  // XCD-aware remap (grid=512, nwg%8==0 -> bijective)
  const int lid = blockIdx.x;
  const int xcd = lid & 7, chunk = lid >> 3;   // chunk 0..63
  const int bm = (xcd * 8 + (chunk >> 3)) * 128;
  const int bn = (chunk & 7) * 128;

  // staging: linear LDS dest, inverse-swizzled global source
  const int rbase = tid >> 3;               // 0..31
  const int sg    = (tid & 7) ^ (rbase & 7);
  const size_t aoff = (size_t)(bm + rbase) * K + sg * 8;
  const size_t boff = (size_t)(bn + rbase) * K + sg * 8;
  const size_t rs32 = (size_t)32 * K;

  auto stage = [&](const ushort_t* gA, const ushort_t* gB, int buf) {
    ushort_t* base = &lds[buf][0];
    ushort_t* lA = base + wave * 512;          // A at elem 0
    ushort_t* lB = base + 8192 + wave * 512;   // B at elem 8192
    gl_lds16(gA,            lA);
    gl_lds16(gA + rs32,     lA + 2048);
    gl_lds16(gA + 2 * rs32, lA + 4096);
    gl_lds16(gA + 3 * rs32, lA + 6144);
    gl_lds16(gB,            lB);
    gl_lds16(gB + rs32,     lB + 2048);
    gl_lds16(gB + 2 * rs32, lB + 4096);
    gl_lds16(gB + 3 * rs32, lB + 6144);
  };

  // fragment read addressing (XOR-swizzled, conflict-free verified R7-R10)
  const int s0   = (kg ^ (fr & 7)) * 16;    // byte slot, ks=0; ks=1 -> ^64
  const int arow = (wm + fr) * 128;
  const int brow = 16384 + (wn + fr) * 128;

  f32x4 acc[4][4], out_acc[4][4];
#pragma unroll
  for (int i = 0; i < 4; i++)
#pragma unroll
    for (int j = 0; j < 4; j++) {
      acc[i][j] = (f32x4){0.f, 0.f, 0.f, 0.f};
      if (NSRC > 1) out_acc[i][j] = (f32x4){0.f, 0.f, 0.f, 0.f};
    }

  // biases preloaded (keeps vmcnt accounting in the K-loop exact)
  float bpre[NSRC][4];
#pragma unroll
  for (int s = 0; s < NSRC; ++s)
#pragma unroll
    for (int ni = 0; ni < 4; ni++)
      bpre[s][ni] = (float)*(const __hip_bfloat16*)
          (args.s[s].bias + bn + wn + ni * 16 + fr);

  const int TPS = K >> 6;          // K-tiles per source (16 or 32)
  const int NT  = TPS * NSRC;

  // two named fragment sets (static indexing)
  bf16x8 af0[4], bf0[4], af1[4], bf1[4];

  auto rdfrag0 = [&](const char* Lb, int ks) {
    const int so = s0 ^ (ks * 64);
#pragma unroll
    for (int m = 0; m < 4; ++m) af0[m] = *(const bf16x8*)(Lb + arow + m * 2048 + so);
#pragma unroll
    for (int n = 0; n < 4; ++n) bf0[n] = *(const bf16x8*)(Lb + brow + n * 2048 + so);
  };
  auto rdfrag1 = [&](const char* Lb, int ks) {
    const int so = s0 ^ (ks * 64);
#pragma unroll
    for (int m = 0; m < 4; ++m) af1[m] = *(const bf16x8*)(Lb + arow + m * 2048 + so);
#pragma unroll
    for (int n = 0; n < 4; ++n) bf1[n] = *(const bf16x8*)(Lb + brow + n * 2048 + so);
  };
  auto mfma16_0 = [&]() {
    __builtin_amdgcn_s_setprio(1);
#pragma unroll
    for (int mi = 0; mi < 4; mi++)
#pragma unroll
      for (int ni = 0; ni < 4; ni++)
        acc[mi][ni] = __builtin_amdgcn_mfma_f32_16x16x32_bf16(
            af0[mi], bf0[ni], acc[mi][ni], 0, 0, 0);
    __builtin_amdgcn_s_setprio(0);
  };
  auto mfma16_1 = [&]() {
    __builtin_amdgcn_s_setprio(1);
#pragma unroll
    for (int mi = 0; mi < 4; mi++)
#pragma unroll
      for (int ni = 0; ni < 4; ni++)
        acc[mi][ni] = __builtin_amdgcn_mfma_f32_16x16x32_bf16(
            af1[mi], bf1[ni], acc[mi][ni], 0, 0, 0);
    __builtin_amdgcn_s_setprio(0);
  };

  // prologue: stage tiles 0,1; wait tile 0 (tile 1's 8 loads stay flying)
  stage(args.s[0].A + aoff, args.s[0].B + boff, 0);
  {
    const int s1 = 1 / TPS, k1 = (1 % TPS) * 64;
    stage(args.s[s1].A + aoff + k1, args.s[s1].B + boff + k1, 1);
  }
  VMC8();
  SBAR();
  rdfrag0((const char*)&lds[0][0], 0);

  int psrc = 2 / TPS, pk0 = (2 % TPS) * 64;  // next tile to stage
  int csrc = 0, ck = 0;
  int cur = 0;

  for (int t = 0; t < NT; ++t) {
    const char* Lb = (const char*)&lds[cur][0];

    // read ks=1 frags (this tile), covered by MFMA on ks=0 frags
    rdfrag1(Lb, 1);
    __builtin_amdgcn_sched_barrier(0);
    mfma16_0();

    // read-retirement fence: buf cur reusable after this barrier
    LGKM0();
    SBAR();

    ck += 64;
    const bool srcEnd = (ck == K);
    const bool more2 = (t + 2 < NT);
    if (more2) {
      stage(args.s[psrc].A + aoff + pk0, args.s[psrc].B + boff + pk0, cur);
      pk0 += 64; if (pk0 == K) { pk0 = 0; ++psrc; }
    }

    // counted vmcnt: tile t+1's 8 loads (issued one full tile ago);
    // tile t+2's 8 stay in flight across the barrier
    if (t + 1 < NT) {
      if (more2) VMC8(); else VMC0();
      SBAR();
      rdfrag0((const char*)&lds[cur ^ 1][0], 0);
    }
    __builtin_amdgcn_sched_barrier(0);
    mfma16_1();

    // source-boundary epilogue
    if (NSRC > 1 && srcEnd) {
      float bb[4];
#pragma unroll
      for (int s = 0; s < NSRC; ++s)
        if (s == csrc) {
#pragma unroll
          for (int ni = 0; ni < 4; ni++) bb[ni] = bpre[s][ni];
        }
#pragma unroll
      for (int ni = 0; ni < 4; ni++)
#pragma unroll
        for (int mi = 0; mi < 4; mi++)
#pragma unroll
          for (int j = 0; j < 4; j++) {
            float v = acc[mi][ni][j] + bb[ni];
            if (RELU) v = fmaxf(v, 0.0f);
            out_acc[mi][ni][j] += v;
            acc[mi][ni][j] = 0.0f;
          }
      ck = 0; ++csrc;
    }

    cur ^= 1;
  }

  // store: C/D layout col = lane&15, row = (lane>>4)*4 + reg (verified R3)
#pragma unroll
  for (int ni = 0; ni < 4; ni++) {
    const int c = bn + wn + ni * 16 + fr;
    if (NGUARD && c >= N_real) continue;
#pragma unroll
    for (int mi = 0; mi < 4; mi++) {
      const int r0 = bm + wm + mi * 16 + kg * 4;
#pragma unroll
      for (int j = 0; j < 4; j++) {
        const size_t idx = (size_t)(r0 + j) * ldc + c;
        float v;
        if (NSRC == 1) {
          v = acc[mi][ni][j] + bpre[0][ni];
          if (RELU) v = fmaxf(v, 0.0f);
        } else {
          v = out_acc[mi][ni][j];
        }
        if (of32) Cf[idx] = v;
        else      C[idx]  = (__hip_bfloat16)v;
      }
    }
  }
}

// ---------------- persistent mega-kernel (plain launch, atomic grid barrier) ----------------
__global__ __launch_bounds__(256, 2) void meganet(MegaArgs ma) {
  __shared__ __align__(16) ushort_t lds[2][16384];
  const int tid = threadIdx.x;
  int* flags = ma.flags;
  int* bar = ma.bar;

  // ---- phase 0: dtype detection (block 0 only; verified R3) ----
  if (blockIdx.x == 0) {
    int* sdet = (int*)&lds[0][0];
    if (tid < 4) sdet[tid] = 0;
    __syncthreads();
    const ushort_t* x  = (const ushort_t*)ma.pe[24].w;   // x source
    const ushort_t* mf = (const ushort_t*)ma.pe[0].m;    // mf source
    int expout = 0, m3f80_even = 0, m3f80_odd = 0, mhi01 = 0;
    for (int k = tid; k < 2048; k += 256) {
      ushort_t w = x[k];
      int e = (w >> 7) & 0xFF;
      if (e < 96 || e > 144) expout++;
      ushort_t mw = mf[k];
      if (mw == 0x3F80) { if (k & 1) m3f80_odd++; else m3f80_even++; }
      if ((mw >> 8) == 1) mhi01++;
    }
    atomicAdd(&sdet[0], expout);
    atomicAdd(&sdet[1], m3f80_even);
    atomicAdd(&sdet[2], m3f80_odd);
    atomicAdd(&sdet[3], mhi01);
    __syncthreads();
    if (tid == 0) {
      flags[0] = (sdet[0] > 100) ? 1 : 0;
      int mmode = 0;
      if (sdet[1] > 100) mmode = 2;
      else if (sdet[2] > 100) mmode = 3;
      else if (sdet[3] > 200) mmode = 1;
      flags[1] = mmode;
    }
  }
  gbar(bar, 0);

  // ---- phase 1: masking + dtype conversion (all blocks; verified R3) ----
  {
    const bool f32 = flags[0] != 0;
    const int mmode = flags[1];
    const int stride = gridDim.x * blockDim.x;
    for (int ei = 0; ei < 25; ++ei) {
      const PrepEnt e = ma.pe[ei];     // uniform index -> kernarg s_load
      const int nch = e.n >> 3;
      for (int ci = blockIdx.x * blockDim.x + tid; ci < nch; ci += stride) {
        const int i = ci << 3;
        ushort_t o[8] = {0, 0, 0, 0, 0, 0, 0, 0};
        if (i < e.valid) {
          ushort_t wb[8];
          if (f32) {
            const float* wp = (const float*)e.w + e.woff + i;
            float4 a = *(const float4*)wp;
            float4 b = *(const float4*)(wp + 4);
            wb[0] = f2b(a.x); wb[1] = f2b(a.y); wb[2] = f2b(a.z); wb[3] = f2b(a.w);
            wb[4] = f2b(b.x); wb[5] = f2b(b.y); wb[6] = f2b(b.z); wb[7] = f2b(b.w);
          } else {
            *(uint4*)wb = *(const uint4*)((const ushort_t*)e.w + e.woff + i);
          }
          unsigned mk = 0xFF;
          if (e.m) {
            mk = 0;
            if (mmode == 0) {
              const int4* mp = (const int4*)((const int*)e.m + e.moff + i);
              int4 a = mp[0], b = mp[1];
              mk = (a.x != 0) | ((a.y != 0) << 1) | ((a.z != 0) << 2) | ((a.w != 0) << 3) |
                   ((b.x != 0) << 4) | ((b.y != 0) << 5) | ((b.z != 0) << 6) | ((b.w != 0) << 7);
            } else if (mmode == 1) {
              const uint2 mv = *(const uint2*)((const unsigned char*)e.m + e.moff + i);
              const unsigned char* mb = (const unsigned char*)&mv;
              for (int j = 0; j < 8; j++) mk |= (mb[j] != 0) << j;
            } else if (mmode == 2) {
              uint4 mv = *(const uint4*)((const ushort_t*)e.m + e.moff + i);
              const ushort_t* ms = (const ushort_t*)&mv;
              for (int j = 0; j < 8; j++) mk |= (ms[j] != 0) << j;
            } else {
              const uint4* mp = (const uint4*)((const unsigned int*)e.m + e.moff + i);
              uint4 a = mp[0], b = mp[1];
              const unsigned* u = (const unsigned*)&a;
              const unsigned* v = (const unsigned*)&b;
              for (int j = 0; j < 4; j++) mk |= (u[j] != 0) << j;
              for (int j = 0; j < 4; j++) mk |= (v[j] != 0) << (4 + j);
            }
          }
#pragma unroll
          for (int j = 0; j < 8; j++) o[j] = ((mk >> j) & 1) ? wb[j] : (ushort_t)0;
        }
        *(uint4*)(e.o + i) = *(uint4*)o;
      }
    }
  }
  gbar(bar, 1);

  // ---- phase 2: the 6 network layers (compile-time instantiations) ----
  gemm_layer<1, true,  false>(ma.a0, ma.C0, nullptr, 2048, 1024, 1024, lds);
  gbar(bar, 2);
  gemm_layer<1, true,  false>(ma.a1, ma.C1, nullptr, 1024, 1024, 1024, lds);
  gbar(bar, 3);
  gemm_layer<2, true,  false>(ma.a2, ma.C2, nullptr, 1024, 1024, 1024, lds);
  gbar(bar, 4);
  gemm_layer<3, true,  false>(ma.a3, ma.C3, nullptr, 1024, 1024, 1024, lds);
  gbar(bar, 5);
  gemm_layer<4, true,  false>(ma.a4, ma.C4, nullptr, 1024, 1024, 1024, lds);
  gbar(bar, 6);
  gemm_layer<1, false, true >(ma.ao, ma.C5, flags,   1024, 1000, 1000, lds);
}

extern "C" void kernel_launch(void* const* d_in, const int* in_sizes, int n_in,
                              void* d_out, int out_size, void* d_ws, size_t ws_size,
                              hipStream_t stream) {
  (void)out_size; (void)ws_size;
  const int Bm = 8192, DIN = 2048, H = 1024, Cn = 1000;
  const size_t HH = (size_t)H * H;

  // ---- size-signature input resolver (verified R3) ----
  struct PO { const void* p; size_t off; };
  PO x{d_in[0], 0}, Wf{d_in[0], 0}, mf{d_in[0], 0}, Wo{d_in[0], 0}, mo{d_in[0], 0};
  PO bf{d_in[0], 0}, bo{d_in[0], 0};
  PO mW[4], mM[4], mB[4], sW[6], sM[6], sB[6];
  for (int i = 0; i < 4; i++) { mW[i] = {d_in[0], 0}; mM[i] = mW[i]; mB[i] = mW[i]; }
  for (int i = 0; i < 6; i++) { sW[i] = {d_in[0], 0}; sM[i] = sW[i]; sB[i] = sW[i]; }

  {
    int c2M = 0, c1M = 0, c1k = 0, cWoMo = 0, c4 = 0, c6 = 0;
    for (int i = 0; i < n_in; i++) {
      const int s = in_sizes[i];
      const void* p = d_in[i];
      switch (s) {
        case 16777216: x = {p, 0}; break;
        case 2097152:  if (c2M++ == 0) Wf = {p, 0}; else mf = {p, 0}; break;
        case 1048576: {
          int j = c1M++;
          if (j < 4)       mW[j]      = {p, 0};
          else if (j < 8)  mM[j - 4]  = {p, 0};
          else if (j < 14) sW[j - 8]  = {p, 0};
          else if (j < 20) sM[j - 14] = {p, 0};
          break;
        }
        case 1024: {
          int j = c1k++;
          if (j == 0)      bf        = {p, 0};
          else if (j < 5)  mB[j - 1] = {p, 0};
          else if (j < 11) sB[j - 5] = {p, 0};
          break;
        }
        case 1024000: if (cWoMo++ == 0) Wo = {p, 0}; else mo = {p, 0}; break;
        case 1000: bo = {p, 0}; break;
        case 4194304:
          for (int t = 0; t < 4; t++) {
            if (c4 == 0) mW[t] = {p, t * HH}; else mM[t] = {p, t * HH};
          }
          c4++; break;
        case 6291456:
          for (int t = 0; t < 6; t++) {
            if (c6 == 0) sW[t] = {p, t * HH}; else sM[t] = {p, t * HH};
          }
          c6++; break;
        case 4096:
          for (int t = 0; t < 4; t++) mB[t] = {p, (size_t)t * H};
          break;
        case 6144:
          for (int t = 0; t < 6; t++) sB[t] = {p, (size_t)t * H};
          break;
        default: break;
      }
    }
  }

  // ---- workspace layout (ushort units) ----
  ushort_t* wsp = (ushort_t*)d_ws;
  size_t off = 0;
  int* bar = (int*)wsp; off += 64;            // 32 ints, zeroed each launch
  int* flags = (int*)(wsp + off); off += 32;
  ushort_t* xc = wsp + off; off += (size_t)Bm * DIN;
  __hip_bfloat16* r[5];
  for (int i = 0; i < 5; i++) { r[i] = (__hip_bfloat16*)(wsp + off); off += (size_t)Bm * H; }
  ushort_t* wWf = wsp + off; off += (size_t)H * DIN;
  ushort_t* wMain[4];
  for (int i = 0; i < 4; i++) { wMain[i] = wsp + off; off += HH; }
  ushort_t* wSkip[6];
  for (int k = 0; k < 6; k++) { wSkip[k] = wsp + off; off += HH; }
  ushort_t* wWo = wsp + off; off += (size_t)1024 * 1024;  // zero-padded to 1024 rows
  ushort_t* cbf_ = wsp + off; off += 1024;
  ushort_t* cmB[4];
  for (int i = 0; i < 4; i++) { cmB[i] = wsp + off; off += 1024; }
  ushort_t* csB[6];
  for (int k = 0; k < 6; k++) { csB[k] = wsp + off; off += 1024; }
  ushort_t* cbo = wsp + off; off += 1024;                 // tail 1000..1023 zeroed

  // ---- mega-args ----
  MegaArgs ma;
  ma.flags = flags;
  ma.bar = bar;
  ma.pe[0]  = { Wf.p, mf.p, wWf, (int)Wf.off, (int)mf.off, H * DIN, H * DIN };
  for (int i = 0; i < 4; i++)
    ma.pe[1 + i] = { mW[i].p, mM[i].p, wMain[i], (int)mW[i].off, (int)mM[i].off, (int)HH, (int)HH };
  for (int k = 0; k < 6; k++)
    ma.pe[5 + k] = { sW[k].p, sM[k].p, wSkip[k], (int)sW[k].off, (int)sM[k].off, (int)HH, (int)HH };
  ma.pe[11] = { Wo.p, mo.p, wWo, (int)Wo.off, (int)mo.off, 1024 * 1024, Cn * H };
  ma.pe[12] = { bf.p, nullptr, cbf_, (int)bf.off, 0, H, H };
  for (int i = 0; i < 4; i++)
    ma.pe[13 + i] = { mB[i].p, nullptr, cmB[i], (int)mB[i].off, 0, H, H };
  for (int k = 0; k < 6; k++)
    ma.pe[17 + k] = { sB[k].p, nullptr, csB[k], (int)sB[k].off, 0, H, H };
  ma.pe[23] = { bo.p, nullptr, cbo, (int)bo.off, 0, 1024, Cn };
  // x conversion: NO MASK (R10's verified prep table; detect reads mf via pe[0].m)
  ma.pe[24] = { x.p, nullptr, xc, (int)x.off, 0, Bm * DIN, Bm * DIN };

  // per-layer GEMM args (unused slots = source 0, never dereferenced beyond NSRC)
  ma.a0.s[0] = { xc, wWf, cbf_ };
  for (int s = 1; s < 4; ++s) ma.a0.s[s] = ma.a0.s[0];
  ma.a1.s[0] = { (ushort_t*)r[0], wMain[0], cmB[0] };
  for (int s = 1; s < 4; ++s) ma.a1.s[s] = ma.a1.s[0];
  ma.a2.s[0] = { (ushort_t*)r[1], wMain[1], cmB[1] };
  ma.a2.s[1] = { (ushort_t*)r[0], wSkip[0], csB[0] };
  ma.a2.s[2] = ma.a2.s[0]; ma.a2.s[3] = ma.a2.s[0];
  ma.a3.s[0] = { (ushort_t*)r[2], wMain[2], cmB[2] };
  ma.a3.s[1] = { (ushort_t*)r[0], wSkip[1], csB[1] };
  ma.a3.s[2] = { (ushort_t*)r[1], wSkip[2], csB[2] };
  ma.a3.s[3] = ma.a3.s[0];
  ma.a4.s[0] = { (ushort_t*)r[3], wMain[3], cmB[3] };
  ma.a4.s[1] = { (ushort_t*)r[0], wSkip[3], csB[3] };
  ma.a4.s[2] = { (ushort_t*)r[1], wSkip[4], csB[4] };
  ma.a4.s[3] = { (ushort_t*)r[2], wSkip[5], csB[5] };
  ma.ao.s[0] = { (ushort_t*)r[4], wWo, cbo };
  for (int s = 1; s < 4; ++s) ma.ao.s[s] = ma.ao.s[0];

  ma.C0 = r[0]; ma.C1 = r[1]; ma.C2 = r[2];
  ma.C3 = r[3]; ma.C4 = r[4]; ma.C5 = d_out;

  // ---- zero the barrier counters, then one plain (graph-capturable) launch ----
  hipMemsetAsync(d_ws, 0, 128, stream);
  meganet<<<dim3(512), dim3(256), 0, stream>>>(ma);
}

// Round 11
// 516.382 us; speedup vs baseline: 3.5608x; 2.0317x over previous
//
#include <hip/hip_runtime.h>
#include <hip/hip_bf16.h>
#include <stdint.h>

// MaskedDeepDAN on MI355X (gfx950). B=8192, D_IN=2048, H=1024, C=1000.
// R17: REVERT to R10 (best verified: 515.2us), per R16's pre-committed
// decision rule. Session findings locked in comments:
//  - GEMM plateau: 26-29% MfmaUtil across R7(4-phase)/R8(straight-line)/
//    R9(half-tile-pipelined)/R10(2 blocks/CU) = the 2-phase LDS-GEMM
//    structural ceiling (~680 TF quadrant). Escapes tried: LDS-free
//    register streaming (R11: latency-fatal, 11% MfmaUtil), 256x128
//    4-phase (R7: barrier-serialized). 256^2 8-phase doesn't fit N=1024
//    (128 blocks = half chip idle).
//  - Fusion wall: persistent mega-kernel (R12-R16) bottoms at 1049us —
//    software grid barriers on 8 non-coherent XCD L2s cost ~70-85us each
//    (512 serialized agent-scope RMWs + per-block L2 wb/inv walks),
//    exceeding the true inter-launch gap. hipLaunchCooperativeKernel is
//    NOT graph-capturable (R12/R13: kernel silently never ran).
// This kernel: BM=128 x BN=128 x BK=64, 256 thr / 4 waves (2Mx2N,
// 64x64/wave), LDS 2x32KB -> 2 blocks/CU, grid 512, bijective XCD remap,
// half-tile-pipelined frags, 2 barriers/tile, counted vmcnt(8) never 0 in
// main loop, lgkm0 read-retirement fence, XOR-swizzled staging/reads
// (bank-conflict 0, verified R7-R10), fused bias+relu multi-source
// epilogue. Prep/detect/resolver/store verified R3-R10.

typedef unsigned short ushort_t;
typedef __bf16 bf16x8 __attribute__((ext_vector_type(8)));
typedef float f32x4 __attribute__((ext_vector_type(4)));

__device__ __forceinline__ void gl_lds16(const void* g, void* l) {
  typedef __attribute__((address_space(1))) void gvoid;
  typedef __attribute__((address_space(3))) void lvoid;
  __builtin_amdgcn_global_load_lds((gvoid*)(void*)g, (lvoid*)l, 16, 0, 0);
}

__device__ __forceinline__ ushort_t f2b(float f) {
  __hip_bfloat16 h = (__hip_bfloat16)f;
  return *(ushort_t*)&h;
}

// ---------------- dtype detection (verified R3) ----------------
// flags[0] = 1 if floats are fp32, 0 if bf16
// flags[1] = mask mode: 0=int32, 1=uint8, 2=bf16(u16), 3=fp32
__global__ void detect_kernel(const ushort_t* x, const ushort_t* mf, int* flags) {
  __shared__ int s[4];
  if (threadIdx.x < 4) s[threadIdx.x] = 0;
  __syncthreads();
  int expout = 0, m3f80_even = 0, m3f80_odd = 0, mhi01 = 0;
  for (int k = threadIdx.x; k < 2048; k += 256) {
    ushort_t w = x[k];
    int e = (w >> 7) & 0xFF;
    if (e < 96 || e > 144) expout++;
    ushort_t mw = mf[k];
    if (mw == 0x3F80) { if (k & 1) m3f80_odd++; else m3f80_even++; }
    if ((mw >> 8) == 1) mhi01++;
  }
  atomicAdd(&s[0], expout);
  atomicAdd(&s[1], m3f80_even);
  atomicAdd(&s[2], m3f80_odd);
  atomicAdd(&s[3], mhi01);
  __syncthreads();
  if (threadIdx.x == 0) {
    flags[0] = (s[0] > 100) ? 1 : 0;
    int mmode = 0;
    if (s[1] > 100) mmode = 2;
    else if (s[2] > 100) mmode = 3;
    else if (s[3] > 200) mmode = 1;
    flags[1] = mmode;
  }
}

// -------- masking + dtype conversion (weights, biases, and x) --------
struct PrepEnt {
  const void* w; size_t woff;
  const void* m; size_t moff;   // nullptr -> no mask
  ushort_t* o;
  int n;
  int valid;                    // i >= valid -> 0
};
struct PrepAll { PrepEnt e[25]; };

__global__ void prep_weights(PrepAll p, const int* flags) {
  const bool f32 = flags[0] != 0;
  const int mmode = flags[1];
  const PrepEnt e = p.e[blockIdx.y];
  const int nch = e.n >> 3;
  const int stride = blockDim.x * gridDim.x;
  for (int ci = blockIdx.x * blockDim.x + threadIdx.x; ci < nch; ci += stride) {
    const int i = ci << 3;
    ushort_t o[8] = {0, 0, 0, 0, 0, 0, 0, 0};
    if (i < e.valid) {
      ushort_t wb[8];
      if (f32) {
        const float* wp = (const float*)e.w + e.woff + i;
        float4 a = *(const float4*)wp;
        float4 b = *(const float4*)(wp + 4);
        wb[0] = f2b(a.x); wb[1] = f2b(a.y); wb[2] = f2b(a.z); wb[3] = f2b(a.w);
        wb[4] = f2b(b.x); wb[5] = f2b(b.y); wb[6] = f2b(b.z); wb[7] = f2b(b.w);
      } else {
        *(uint4*)wb = *(const uint4*)((const ushort_t*)e.w + e.woff + i);
      }
      unsigned mk = 0xFF;
      if (e.m) {
        mk = 0;
        if (mmode == 0) {
          const int4* mp = (const int4*)((const int*)e.m + e.moff + i);
          int4 a = mp[0], b = mp[1];
          mk = (a.x != 0) | ((a.y != 0) << 1) | ((a.z != 0) << 2) | ((a.w != 0) << 3) |
               ((b.x != 0) << 4) | ((b.y != 0) << 5) | ((b.z != 0) << 6) | ((b.w != 0) << 7);
        } else if (mmode == 1) {
          const uint2 mv = *(const uint2*)((const unsigned char*)e.m + e.moff + i);
          const unsigned char* mb = (const unsigned char*)&mv;
          for (int j = 0; j < 8; j++) mk |= (mb[j] != 0) << j;
        } else if (mmode == 2) {
          uint4 mv = *(const uint4*)((const ushort_t*)e.m + e.moff + i);
          const ushort_t* ms = (const ushort_t*)&mv;
          for (int j = 0; j < 8; j++) mk |= (ms[j] != 0) << j;
        } else {
          const uint4* mp = (const uint4*)((const unsigned int*)e.m + e.moff + i);
          uint4 a = mp[0], b = mp[1];
          const unsigned* u = (const unsigned*)&a;
          const unsigned* v = (const unsigned*)&b;
          for (int j = 0; j < 4; j++) mk |= (u[j] != 0) << j;
          for (int j = 0; j < 4; j++) mk |= (v[j] != 0) << (4 + j);
        }
      }
#pragma unroll
      for (int j = 0; j < 8; j++) o[j] = ((mk >> j) & 1) ? wb[j] : (ushort_t)0;
    }
    *(uint4*)(e.o + i) = *(uint4*)o;
  }
}

// ---------------- fused multi-source GEMM, 2-blocks/CU pipelined ----------------
// C[M,N] = sum_s relu(A_s[M,K] * B_s[N,K]^T + bias_s)
// grid = 512 blocks (BM=128 x BN=128 over M=8192, N_pad=1024), block = 256.
struct GemmSrc { const ushort_t* A; const ushort_t* B; const ushort_t* bias; };
struct GemmArgs { GemmSrc s[4]; };

#define SBAR()  asm volatile("s_barrier" ::: "memory")
#define LGKM0() asm volatile("s_waitcnt lgkmcnt(0)" ::: "memory")
#define VMC8()  asm volatile("s_waitcnt vmcnt(8)" ::: "memory")
#define VMC0()  asm volatile("s_waitcnt vmcnt(0)" ::: "memory")

template <int NSRC, bool RELU, bool NGUARD>
__launch_bounds__(256, 2)
__global__ void gemm_multi(GemmArgs args, void* Cv, const int* of32flag,
                           int K, int N_real, int ldc)
{
  // per buffer: A 128x64 bf16 (8192 el) + B 128x64 bf16 (8192 el) = 32KB
  __shared__ __align__(16) ushort_t lds[2][16384];

  const bool of32 = (of32flag != nullptr) && (of32flag[0] != 0);
  __hip_bfloat16* C = (__hip_bfloat16*)Cv;
  float* Cf = (float*)Cv;

  const int tid  = threadIdx.x;
  const int lane = tid & 63;
  const int wave = tid >> 6;         // 0..3
  const int wm = (wave >> 1) * 64;   // 0,64
  const int wn = (wave & 1) * 64;    // 0,64
  const int fr = lane & 15;
  const int kg = lane >> 4;

  // XCD-aware remap (grid=512, nwg%8==0 -> bijective): XCD x = lid&7 owns
  // 8 M-panels x 8 N-tiles; the 8 blocks sharing one A-panel are on the
  // SAME XCD -> A fetched once per XCD L2.
  const int lid = blockIdx.x;
  const int xcd = lid & 7, chunk = lid >> 3;   // chunk 0..63
  const int bm = (xcd * 8 + (chunk >> 3)) * 128;
  const int bn = (chunk & 7) * 128;

  // -------- staging addressing: linear LDS dest, inverse-swizzled source.
  // thread t covers row (t>>3)+32j, 16B-slot (t&7); global slot
  // sg = (t&7) ^ (row&7) = (t&7) ^ ((t>>3)&7)  (32j == 0 mod 8).
  const int rbase = tid >> 3;               // 0..31
  const int sg    = (tid & 7) ^ (rbase & 7);
  const size_t aoff = (size_t)(bm + rbase) * K + sg * 8;
  const size_t boff = (size_t)(bn + rbase) * K + sg * 8;
  const size_t rs32 = (size_t)32 * K;

  auto stage = [&](const ushort_t* gA, const ushort_t* gB, int buf) {
    ushort_t* base = &lds[buf][0];
    ushort_t* lA = base + wave * 512;          // A at elem 0
    ushort_t* lB = base + 8192 + wave * 512;   // B at elem 8192
    gl_lds16(gA,            lA);
    gl_lds16(gA + rs32,     lA + 2048);
    gl_lds16(gA + 2 * rs32, lA + 4096);
    gl_lds16(gA + 3 * rs32, lA + 6144);
    gl_lds16(gB,            lB);
    gl_lds16(gB + rs32,     lB + 2048);
    gl_lds16(gB + 2 * rs32, lB + 4096);
    gl_lds16(gB + 3 * rs32, lB + 6144);
  };

  // -------- fragment read addressing (XOR-swizzled, row&7 == fr&7) --------
  const int s0   = (kg ^ (fr & 7)) * 16;    // byte slot, ks=0; ks=1 -> ^64
  const int arow = (wm + fr) * 128;         // byte offset of A row
  const int brow = 16384 + (wn + fr) * 128; // byte offset of B row

  f32x4 acc[4][4], out_acc[4][4];
#pragma unroll
  for (int i = 0; i < 4; i++)
#pragma unroll
    for (int j = 0; j < 4; j++) {
      acc[i][j] = (f32x4){0.f, 0.f, 0.f, 0.f};
      if (NSRC > 1) out_acc[i][j] = (f32x4){0.f, 0.f, 0.f, 0.f};
    }

  // biases preloaded (keeps vmcnt accounting in the K-loop exact)
  float bpre[NSRC][4];
#pragma unroll
  for (int s = 0; s < NSRC; ++s)
#pragma unroll
    for (int ni = 0; ni < 4; ni++)
      bpre[s][ni] = (float)*(const __hip_bfloat16*)
          (args.s[s].bias + bn + wn + ni * 16 + fr);

  const int TPS = K >> 6;          // K-tiles per source (16 or 32)
  const int NT  = TPS * NSRC;

  // two named fragment sets (static indexing)
  bf16x8 af0[4], bf0[4], af1[4], bf1[4];

  auto rdfrag0 = [&](const char* Lb, int ks) {
    const int so = s0 ^ (ks * 64);
#pragma unroll
    for (int m = 0; m < 4; ++m) af0[m] = *(const bf16x8*)(Lb + arow + m * 2048 + so);
#pragma unroll
    for (int n = 0; n < 4; ++n) bf0[n] = *(const bf16x8*)(Lb + brow + n * 2048 + so);
  };
  auto rdfrag1 = [&](const char* Lb, int ks) {
    const int so = s0 ^ (ks * 64);
#pragma unroll
    for (int m = 0; m < 4; ++m) af1[m] = *(const bf16x8*)(Lb + arow + m * 2048 + so);
#pragma unroll
    for (int n = 0; n < 4; ++n) bf1[n] = *(const bf16x8*)(Lb + brow + n * 2048 + so);
  };
  auto mfma16_0 = [&]() {
    __builtin_amdgcn_s_setprio(1);
#pragma unroll
    for (int mi = 0; mi < 4; mi++)
#pragma unroll
      for (int ni = 0; ni < 4; ni++)
        acc[mi][ni] = __builtin_amdgcn_mfma_f32_16x16x32_bf16(
            af0[mi], bf0[ni], acc[mi][ni], 0, 0, 0);
    __builtin_amdgcn_s_setprio(0);
  };
  auto mfma16_1 = [&]() {
    __builtin_amdgcn_s_setprio(1);
#pragma unroll
    for (int mi = 0; mi < 4; mi++)
#pragma unroll
      for (int ni = 0; ni < 4; ni++)
        acc[mi][ni] = __builtin_amdgcn_mfma_f32_16x16x32_bf16(
            af1[mi], bf1[ni], acc[mi][ni], 0, 0, 0);
    __builtin_amdgcn_s_setprio(0);
  };

  // prologue: stage tiles 0,1; wait tile 0 (leave tile 1's 8 loads flying);
  // pre-read ks=0 fragments of tile 0.
  stage(args.s[0].A + aoff, args.s[0].B + boff, 0);
  {
    const int s1 = 1 / TPS, k1 = (1 % TPS) * 64;
    stage(args.s[s1].A + aoff + k1, args.s[s1].B + boff + k1, 1);
  }
  VMC8();
  SBAR();
  rdfrag0((const char*)&lds[0][0], 0);

  int psrc = 2 / TPS, pk0 = (2 % TPS) * 64;  // next tile to stage
  int csrc = 0, ck = 0;
  int cur = 0;

  for (int t = 0; t < NT; ++t) {
    const char* Lb = (const char*)&lds[cur][0];

    // ---- read ks=1 frags (this tile), covered by MFMA on ks=0 frags ----
    rdfrag1(Lb, 1);
    __builtin_amdgcn_sched_barrier(0);   // pin reads above the MFMA block
    mfma16_0();                          // compiler inserts counted lgkm wait

    // ---- read-retirement fence: all waves' ds_reads of buf cur retired ->
    // safe to overwrite with tile t+2.
    LGKM0();
    SBAR();

    ck += 64;
    const bool srcEnd = (ck == K);
    const bool more2 = (t + 2 < NT);
    if (more2) {
      stage(args.s[psrc].A + aoff + pk0, args.s[psrc].B + boff + pk0, cur);
      pk0 += 64; if (pk0 == K) { pk0 = 0; ++psrc; }
    }

    // ---- counted vmcnt: tile t+1's 8 loads (issued one full tile ago);
    // tile t+2's 8 stay in flight across the barrier. ----
    if (t + 1 < NT) {
      if (more2) VMC8(); else VMC0();
      SBAR();
      // read ks=0 frags of tile t+1 (other buffer), covered by MFMA(ks=1)
      rdfrag0((const char*)&lds[cur ^ 1][0], 0);
    }
    __builtin_amdgcn_sched_barrier(0);   // pin reads above the MFMA block
    mfma16_1();

    // source-boundary epilogue (acc complete only after the ks=1 block)
    if (NSRC > 1 && srcEnd) {
      float bb[4];
#pragma unroll
      for (int s = 0; s < NSRC; ++s)
        if (s == csrc) {
#pragma unroll
          for (int ni = 0; ni < 4; ni++) bb[ni] = bpre[s][ni];
        }
#pragma unroll
      for (int ni = 0; ni < 4; ni++)
#pragma unroll
        for (int mi = 0; mi < 4; mi++)
#pragma unroll
          for (int j = 0; j < 4; j++) {
            float v = acc[mi][ni][j] + bb[ni];
            if (RELU) v = fmaxf(v, 0.0f);
            out_acc[mi][ni][j] += v;
            acc[mi][ni][j] = 0.0f;
          }
      ck = 0; ++csrc;
    }

    cur ^= 1;
  }

  // store: C/D layout col = lane&15, row = (lane>>4)*4 + reg  (verified R3)
#pragma unroll
  for (int ni = 0; ni < 4; ni++) {
    const int c = bn + wn + ni * 16 + fr;
    if (NGUARD && c >= N_real) continue;
#pragma unroll
    for (int mi = 0; mi < 4; mi++) {
      const int r0 = bm + wm + mi * 16 + kg * 4;
#pragma unroll
      for (int j = 0; j < 4; j++) {
        const size_t idx = (size_t)(r0 + j) * ldc + c;
        float v;
        if (NSRC == 1) {
          v = acc[mi][ni][j] + bpre[0][ni];
          if (RELU) v = fmaxf(v, 0.0f);
        } else {
          v = out_acc[mi][ni][j];
        }
        if (of32) Cf[idx] = v;
        else      C[idx]  = (__hip_bfloat16)v;
      }
    }
  }
}

extern "C" void kernel_launch(void* const* d_in, const int* in_sizes, int n_in,
                              void* d_out, int out_size, void* d_ws, size_t ws_size,
                              hipStream_t stream) {
  (void)out_size; (void)ws_size;
  const int Bm = 8192, DIN = 2048, H = 1024, Cn = 1000;
  const size_t HH = (size_t)H * H;

  // ---- size-signature input resolver (verified R3) ----
  struct PO { const void* p; size_t off; };
  PO x{d_in[0], 0}, Wf{d_in[0], 0}, mf{d_in[0], 0}, Wo{d_in[0], 0}, mo{d_in[0], 0};
  PO bf{d_in[0], 0}, bo{d_in[0], 0};
  PO mW[4], mM[4], mB[4], sW[6], sM[6], sB[6];
  for (int i = 0; i < 4; i++) { mW[i] = {d_in[0], 0}; mM[i] = mW[i]; mB[i] = mW[i]; }
  for (int i = 0; i < 6; i++) { sW[i] = {d_in[0], 0}; sM[i] = sW[i]; sB[i] = sW[i]; }

  {
    int c2M = 0, c1M = 0, c1k = 0, cWoMo = 0, c4 = 0, c6 = 0;
    for (int i = 0; i < n_in; i++) {
      const int s = in_sizes[i];
      const void* p = d_in[i];
      switch (s) {
        case 16777216: x = {p, 0}; break;
        case 2097152:  if (c2M++ == 0) Wf = {p, 0}; else mf = {p, 0}; break;
        case 1048576: {
          int j = c1M++;
          if (j < 4)       mW[j]      = {p, 0};
          else if (j < 8)  mM[j - 4]  = {p, 0};
          else if (j < 14) sW[j - 8]  = {p, 0};
          else if (j < 20) sM[j - 14] = {p, 0};
          break;
        }
        case 1024: {
          int j = c1k++;
          if (j == 0)      bf        = {p, 0};
          else if (j < 5)  mB[j - 1] = {p, 0};
          else if (j < 11) sB[j - 5] = {p, 0};
          break;
        }
        case 1024000: if (cWoMo++ == 0) Wo = {p, 0}; else mo = {p, 0}; break;
        case 1000: bo = {p, 0}; break;
        case 4194304:
          for (int t = 0; t < 4; t++) {
            if (c4 == 0) mW[t] = {p, t * HH}; else mM[t] = {p, t * HH};
          }
          c4++; break;
        case 6291456:
          for (int t = 0; t < 6; t++) {
            if (c6 == 0) sW[t] = {p, t * HH}; else sM[t] = {p, t * HH};
          }
          c6++; break;
        case 4096:
          for (int t = 0; t < 4; t++) mB[t] = {p, (size_t)t * H};
          break;
        case 6144:
          for (int t = 0; t < 6; t++) sB[t] = {p, (size_t)t * H};
          break;
        default: break;
      }
    }
  }

  // ---- workspace layout (ushort units) ----
  ushort_t* wsp = (ushort_t*)d_ws;
  size_t off = 0;
  int* flags = (int*)wsp; off += 32;
  ushort_t* xc = wsp + off; off += (size_t)Bm * DIN;
  __hip_bfloat16* r[5];
  for (int i = 0; i < 5; i++) { r[i] = (__hip_bfloat16*)(wsp + off); off += (size_t)Bm * H; }
  ushort_t* wWf = wsp + off; off += (size_t)H * DIN;
  ushort_t* wMain[4];
  for (int i = 0; i < 4; i++) { wMain[i] = wsp + off; off += HH; }
  ushort_t* wSkip[6];
  for (int k = 0; k < 6; k++) { wSkip[k] = wsp + off; off += HH; }
  ushort_t* wWo = wsp + off; off += (size_t)1024 * 1024;  // zero-padded to 1024 rows
  ushort_t* cbf_ = wsp + off; off += 1024;
  ushort_t* cmB[4];
  for (int i = 0; i < 4; i++) { cmB[i] = wsp + off; off += 1024; }
  ushort_t* csB[6];
  for (int k = 0; k < 6; k++) { csB[k] = wsp + off; off += 1024; }
  ushort_t* cbo = wsp + off; off += 1024;                 // tail 1000..1023 zeroed

  // ---- launches ----
  detect_kernel<<<1, 256, 0, stream>>>((const ushort_t*)x.p, (const ushort_t*)mf.p, flags);

  PrepAll p;
  p.e[0]  = { Wf.p, Wf.off, mf.p, mf.off, wWf, H * DIN, H * DIN };
  for (int i = 0; i < 4; i++)
    p.e[1 + i] = { mW[i].p, mW[i].off, mM[i].p, mM[i].off, wMain[i], (int)HH, (int)HH };
  for (int k = 0; k < 6; k++)
    p.e[5 + k] = { sW[k].p, sW[k].off, sM[k].p, sM[k].off, wSkip[k], (int)HH, (int)HH };
  p.e[11] = { Wo.p, Wo.off, mo.p, mo.off, wWo, 1024 * 1024, Cn * H };
  p.e[12] = { bf.p, bf.off, nullptr, 0, cbf_, H, H };
  for (int i = 0; i < 4; i++)
    p.e[13 + i] = { mB[i].p, mB[i].off, nullptr, 0, cmB[i], H, H };
  for (int k = 0; k < 6; k++)
    p.e[17 + k] = { sB[k].p, sB[k].off, nullptr, 0, csB[k], H, H };
  p.e[23] = { bo.p, bo.off, nullptr, 0, cbo, 1024, Cn };
  p.e[24] = { x.p, x.off, nullptr, 0, xc, Bm * DIN, Bm * DIN };   // x conversion
  prep_weights<<<dim3(256, 25), dim3(256), 0, stream>>>(p, flags);

  const dim3 g(512), b(256);

  GemmArgs a0; a0.s[0] = { xc, wWf, cbf_ };
  gemm_multi<1, true, false><<<g, b, 0, stream>>>(a0, r[0], nullptr, DIN, H, H);

  GemmArgs a1; a1.s[0] = { (ushort_t*)r[0], wMain[0], cmB[0] };
  gemm_multi<1, true, false><<<g, b, 0, stream>>>(a1, r[1], nullptr, H, H, H);

  GemmArgs a2;
  a2.s[0] = { (ushort_t*)r[1], wMain[1], cmB[1] };
  a2.s[1] = { (ushort_t*)r[0], wSkip[0], csB[0] };
  gemm_multi<2, true, false><<<g, b, 0, stream>>>(a2, r[2], nullptr, H, H, H);

  GemmArgs a3;
  a3.s[0] = { (ushort_t*)r[2], wMain[2], cmB[2] };
  a3.s[1] = { (ushort_t*)r[0], wSkip[1], csB[1] };
  a3.s[2] = { (ushort_t*)r[1], wSkip[2], csB[2] };
  gemm_multi<3, true, false><<<g, b, 0, stream>>>(a3, r[3], nullptr, H, H, H);

  GemmArgs a4;
  a4.s[0] = { (ushort_t*)r[3], wMain[3], cmB[3] };
  a4.s[1] = { (ushort_t*)r[0], wSkip[3], csB[3] };
  a4.s[2] = { (ushort_t*)r[1], wSkip[4], csB[4] };
  a4.s[3] = { (ushort_t*)r[2], wSkip[5], csB[5] };
  gemm_multi<4, true, false><<<g, b, 0, stream>>>(a4, r[4], nullptr, H, H, H);

  GemmArgs ao; ao.s[0] = { (ushort_t*)r[4], wWo, cbo };
  gemm_multi<1, false, true><<<g, b, 0, stream>>>(ao, d_out, flags, H, Cn, Cn);
}